// Round 1
// baseline (1486.183 us; speedup 1.0000x reference)
//
#include <hip/hip_runtime.h>
#include <math.h>

// Problem constants (match reference)
#define NN 50000   // nodes
#define EE 800000  // edges
#define FF 128     // node features
#define CC 11      // spline coeffs per feature (G+K)
#define CHN 12     // CC + 1 (silu channel folded in)
#define O2 256     // combined outputs: 128 src-proj + 128 dst-proj

// grid point i (i = 0..14): uniform grid on [-1,1] extended by K=3, h=0.25
__device__ __forceinline__ float gpt(int i) { return 0.25f * (float)i - 1.75f; }

// Cox-de Boor K=3 bases (11 values) + silu(x) as channel 11
__device__ __forceinline__ void kan_basis(float xv, float* out) {
  float b[14];
#pragma unroll
  for (int i = 0; i < 14; ++i)
    b[i] = (xv >= gpt(i) && xv < gpt(i + 1)) ? 1.0f : 0.0f;
#pragma unroll
  for (int j = 1; j <= 3; ++j) {
    float inv = 1.0f / (0.25f * (float)j);
#pragma unroll
    for (int i = 0; i + j < 14; ++i)
      b[i] = (xv - gpt(i)) * inv * b[i] + (gpt(i + j + 1) - xv) * inv * b[i + 1];
  }
#pragma unroll
  for (int c = 0; c < 11; ++c) out[c] = b[c];
  out[11] = xv / (1.0f + expf(-xv));  // silu
}

// Repack weights K-major: Wt[f][ch][o2], ch 0..10 = spline, ch 11 = base
__global__ __launch_bounds__(256) void repack_kernel(
    const float* __restrict__ bws, const float* __restrict__ sws,
    const float* __restrict__ bwd, const float* __restrict__ swd,
    float* __restrict__ Wt) {
  int idx = blockIdx.x * 256 + threadIdx.x;
  if (idx >= FF * CHN * O2) return;
  int o2 = idx & 255;
  int ch = (idx >> 8) % CHN;
  int f = idx / (O2 * CHN);
  const float* bw = (o2 < 128) ? bws : bwd;
  const float* sw = (o2 < 128) ? sws : swd;
  int o = o2 & 127;
  float v = (ch == 11) ? bw[o * FF + f] : sw[(o * FF + f) * CC + ch];
  Wt[idx] = v;
}

// Fused KAN projection GEMM: proj[n][0..128)=sp, proj[n][128..256)=dp
// Block: 64 nodes x 256 outputs; K=1536 in chunks of 48 (4 features x 12 ch)
__global__ __launch_bounds__(256) void proj_kernel(
    const float* __restrict__ x, const float* __restrict__ Wt,
    float* __restrict__ proj) {
  __shared__ float Bt[64][48];      // 12 KB
  __shared__ float Wtile[48][O2];   // 48 KB
  const int t = threadIdx.x;
  const int block0 = blockIdx.x * 64;
  const int ng = t >> 4;   // 16 node groups of 4
  const int og = t & 15;   // 16 output groups of 16
  const int n_stage = t & 63;
  const int fi = t >> 6;   // 0..3

  float acc[4][16];
#pragma unroll
  for (int j = 0; j < 4; ++j)
#pragma unroll
    for (int i = 0; i < 16; ++i) acc[j][i] = 0.f;

  for (int kc = 0; kc < 32; ++kc) {
    __syncthreads();
    {  // stage B-spline tile: thread -> (node, feature)
      int f = kc * 4 + fi;
      int node = block0 + n_stage;
      float xv = (node < NN) ? x[node * FF + f] : 0.f;
      float vals[12];
      kan_basis(xv, vals);
#pragma unroll
      for (int c = 0; c < 12; ++c) Bt[n_stage][fi * 12 + c] = vals[c];
    }
    {  // stage W tile: 48*256 floats contiguous, fully coalesced float4
      const float4* src = (const float4*)(Wt + (size_t)kc * 48 * O2);
      float4* dst = (float4*)(&Wtile[0][0]);
#pragma unroll
      for (int i = 0; i < 12; ++i) dst[i * 256 + t] = src[i * 256 + t];
    }
    __syncthreads();
#pragma unroll 4
    for (int kk = 0; kk < 48; ++kk) {
      float4 w0 = *(const float4*)(&Wtile[kk][og * 16 + 0]);
      float4 w1 = *(const float4*)(&Wtile[kk][og * 16 + 4]);
      float4 w2 = *(const float4*)(&Wtile[kk][og * 16 + 8]);
      float4 w3 = *(const float4*)(&Wtile[kk][og * 16 + 12]);
      float bv[4];
#pragma unroll
      for (int j = 0; j < 4; ++j) bv[j] = Bt[ng * 4 + j][kk];
#pragma unroll
      for (int j = 0; j < 4; ++j) {
        acc[j][0]  += bv[j] * w0.x; acc[j][1]  += bv[j] * w0.y;
        acc[j][2]  += bv[j] * w0.z; acc[j][3]  += bv[j] * w0.w;
        acc[j][4]  += bv[j] * w1.x; acc[j][5]  += bv[j] * w1.y;
        acc[j][6]  += bv[j] * w1.z; acc[j][7]  += bv[j] * w1.w;
        acc[j][8]  += bv[j] * w2.x; acc[j][9]  += bv[j] * w2.y;
        acc[j][10] += bv[j] * w2.z; acc[j][11] += bv[j] * w2.w;
        acc[j][12] += bv[j] * w3.x; acc[j][13] += bv[j] * w3.y;
        acc[j][14] += bv[j] * w3.z; acc[j][15] += bv[j] * w3.w;
      }
    }
  }
#pragma unroll
  for (int j = 0; j < 4; ++j) {
    int node = block0 + ng * 4 + j;
    if (node < NN) {
      float4* dst = (float4*)(proj + (size_t)node * O2 + og * 16);
      dst[0] = make_float4(acc[j][0], acc[j][1], acc[j][2], acc[j][3]);
      dst[1] = make_float4(acc[j][4], acc[j][5], acc[j][6], acc[j][7]);
      dst[2] = make_float4(acc[j][8], acc[j][9], acc[j][10], acc[j][11]);
      dst[3] = make_float4(acc[j][12], acc[j][13], acc[j][14], acc[j][15]);
    }
  }
}

// Wave-per-edge: attn scores -> exp (no max shift: cancels in alpha) -> denom
__global__ __launch_bounds__(256) void edge_attn_kernel(
    const float* __restrict__ proj, const int* __restrict__ ei,
    const float* __restrict__ av, float* __restrict__ p,
    float* __restrict__ denom) {
  int e = blockIdx.x * 4 + (threadIdx.x >> 6);
  if (e >= EE) return;
  int lane = threadIdx.x & 63;
  int s = ei[e];
  int d = ei[EE + e];
  const float* sps = proj + (size_t)s * O2;
  const float* dps = proj + (size_t)d * O2 + 128;
  float a1 = av[lane], a2 = av[64 + lane];
  float v1 = sps[lane] + dps[lane];
  float v2 = sps[64 + lane] + dps[64 + lane];
  v1 = (v1 >= 0.f) ? v1 : 0.2f * v1;  // leaky relu
  v2 = (v2 >= 0.f) ? v2 : 0.2f * v2;
  v1 *= a1;
  v2 *= a2;
#pragma unroll
  for (int off = 1; off < 32; off <<= 1) {  // reduce within 32-lane groups
    v1 += __shfl_xor(v1, off, 64);
    v2 += __shfl_xor(v2, off, 64);
  }
  if ((lane & 31) == 0) {
    int h = lane >> 5;  // 0 or 1
    float p1 = expf(v1), p2 = expf(v2);
    p[(size_t)e * 4 + h] = p1;
    p[(size_t)e * 4 + 2 + h] = p2;
    atomicAdd(&denom[(size_t)d * 4 + h], p1);
    atomicAdd(&denom[(size_t)d * 4 + 2 + h], p2);
  }
}

// Wave-per-edge: alpha = p/denom; scatter sp[src]*alpha into agg (=d_out)
__global__ __launch_bounds__(256) void edge_aggr_kernel(
    const float* __restrict__ proj, const int* __restrict__ ei,
    const float* __restrict__ p, const float* __restrict__ denom,
    float* __restrict__ agg) {
  int e = blockIdx.x * 4 + (threadIdx.x >> 6);
  if (e >= EE) return;
  int lane = threadIdx.x & 63;
  int s = ei[e];
  int d = ei[EE + e];
  int h1 = lane >> 5;
  float alpha1 = p[(size_t)e * 4 + h1] / (denom[(size_t)d * 4 + h1] + 1e-16f);
  float alpha2 = p[(size_t)e * 4 + 2 + h1] / (denom[(size_t)d * 4 + 2 + h1] + 1e-16f);
  const float* sps = proj + (size_t)s * O2;
  atomicAdd(&agg[(size_t)d * 128 + lane], sps[lane] * alpha1);
  atomicAdd(&agg[(size_t)d * 128 + 64 + lane], sps[64 + lane] * alpha2);
}

// Residual + bias + PReLU, in-place on d_out
__global__ __launch_bounds__(256) void finalize_kernel(
    const float* __restrict__ x, const float* __restrict__ bias,
    const float* __restrict__ pa, float* __restrict__ out) {
  int i = blockIdx.x * 256 + threadIdx.x;
  if (i >= NN * FF) return;
  float v = out[i] + x[i] + bias[i & 127];
  float a = pa[0];
  out[i] = (v >= 0.f) ? v : a * v;
}

extern "C" void kernel_launch(void* const* d_in, const int* in_sizes, int n_in,
                              void* d_out, int out_size, void* d_ws, size_t ws_size,
                              hipStream_t stream) {
  const float* x = (const float*)d_in[0];
  const int* ei = (const int*)d_in[1];
  const float* bws = (const float*)d_in[2];
  const float* sws = (const float*)d_in[3];
  const float* bwd = (const float*)d_in[4];
  const float* swd = (const float*)d_in[5];
  const float* av = (const float*)d_in[6];
  const float* bias = (const float*)d_in[7];
  const float* pa = (const float*)d_in[8];

  // ws layout (floats): Wt[393216] | proj[50000*256] | p[800000*4] | denom[50000*4]
  float* Wt = (float*)d_ws;
  float* proj = Wt + (size_t)FF * CHN * O2;
  float* p = proj + (size_t)NN * O2;
  float* denom = p + (size_t)EE * 4;

  hipMemsetAsync(denom, 0, (size_t)NN * 4 * sizeof(float), stream);
  hipMemsetAsync(d_out, 0, (size_t)out_size * sizeof(float), stream);

  repack_kernel<<<(FF * CHN * O2 + 255) / 256, 256, 0, stream>>>(bws, sws, bwd, swd, Wt);
  proj_kernel<<<(NN + 63) / 64, 256, 0, stream>>>(x, Wt, proj);
  edge_attn_kernel<<<EE / 4, 256, 0, stream>>>(proj, ei, av, p, denom);
  edge_aggr_kernel<<<EE / 4, 256, 0, stream>>>(proj, ei, p, denom, (float*)d_out);
  finalize_kernel<<<(NN * FF + 255) / 256, 256, 0, stream>>>(x, bias, pa, (float*)d_out);
}

// Round 2
// 1182.058 us; speedup vs baseline: 1.2573x; 1.2573x over previous
//
#include <hip/hip_runtime.h>
#include <math.h>

// Problem constants (match reference)
#define NN 50000   // nodes
#define EE 800000  // edges
#define FF 128     // node features
#define CC 11      // spline coeffs per feature (G+K)
#define CHN 12     // CC + 1 (silu channel folded in)
#define O2 256     // combined outputs: 128 src-proj + 128 dst-proj

// grid point i (i = 0..14): uniform grid on [-1,1] extended by K=3, h=0.25
__device__ __forceinline__ float gpt(int i) { return 0.25f * (float)i - 1.75f; }

// Cox-de Boor K=3 bases (11 values) + silu(x) as channel 11
__device__ __forceinline__ void kan_basis(float xv, float* out) {
  float b[14];
#pragma unroll
  for (int i = 0; i < 14; ++i)
    b[i] = (xv >= gpt(i) && xv < gpt(i + 1)) ? 1.0f : 0.0f;
#pragma unroll
  for (int j = 1; j <= 3; ++j) {
    float inv = 1.0f / (0.25f * (float)j);
#pragma unroll
    for (int i = 0; i + j < 14; ++i)
      b[i] = (xv - gpt(i)) * inv * b[i] + (gpt(i + j + 1) - xv) * inv * b[i + 1];
  }
#pragma unroll
  for (int c = 0; c < 11; ++c) out[c] = b[c];
  out[11] = xv / (1.0f + expf(-xv));  // silu
}

// Repack weights K-major: Wt[f][ch][o2], ch 0..10 = spline, ch 11 = base
__global__ __launch_bounds__(256) void repack_kernel(
    const float* __restrict__ bws, const float* __restrict__ sws,
    const float* __restrict__ bwd, const float* __restrict__ swd,
    float* __restrict__ Wt) {
  int idx = blockIdx.x * 256 + threadIdx.x;
  if (idx >= FF * CHN * O2) return;
  int o2 = idx & 255;
  int ch = (idx >> 8) % CHN;
  int f = idx / (O2 * CHN);
  const float* bw = (o2 < 128) ? bws : bwd;
  const float* sw = (o2 < 128) ? sws : swd;
  int o = o2 & 127;
  float v = (ch == 11) ? bw[o * FF + f] : sw[(o * FF + f) * CC + ch];
  Wt[idx] = v;
}

// Fused KAN projection GEMM: proj[n][0..128)=sp, proj[n][128..256)=dp
// Block: 64 nodes x 256 outputs; K=1536 in chunks of 24 (2 features x 12 ch).
// Thread t: nodes (t>>4)*4 .. +3, cols (t&15)*4 + r*64 (r=0..3).
// All LDS reads are lane-contiguous ds_read_b128 -> conflict-free (2-way max).
__global__ __launch_bounds__(256) void proj_kernel(
    const float* __restrict__ x, const float* __restrict__ Wt,
    float* __restrict__ proj) {
  __shared__ float Bt[24][64];      // transposed basis [k-row][node], 6 KB
  __shared__ float Wtile[24][O2];   // 24 KB
  const int t = threadIdx.x;
  const int block0 = blockIdx.x * 64;
  const int og = t & 15;   // col group
  const int ng = t >> 4;   // node group (0..15)

  float acc[4][16];
#pragma unroll
  for (int j = 0; j < 4; ++j)
#pragma unroll
    for (int i = 0; i < 16; ++i) acc[j][i] = 0.f;

  for (int kc = 0; kc < 64; ++kc) {
    __syncthreads();
    if (t < 128) {  // stage basis, transposed: Bt[fi*12+c][node]
      int fi = t >> 6;       // 0..1
      int node = t & 63;
      int f = kc * 2 + fi;
      int gn = block0 + node;
      float xv = (gn < NN) ? x[(size_t)gn * FF + f] : 0.f;
      float vals[12];
      kan_basis(xv, vals);
#pragma unroll
      for (int c = 0; c < 12; ++c) Bt[fi * 12 + c][node] = vals[c];
    }
    {  // stage W tile: 24*256 floats contiguous, coalesced float4
      const float4* src = (const float4*)(Wt + (size_t)kc * 24 * O2);
      float4* dst = (float4*)(&Wtile[0][0]);
#pragma unroll
      for (int i = 0; i < 6; ++i) dst[i * 256 + t] = src[i * 256 + t];
    }
    __syncthreads();
#pragma unroll 4
    for (int kk = 0; kk < 24; ++kk) {
      float4 bv = *(const float4*)(&Bt[kk][ng * 4]);
      float4 w0 = *(const float4*)(&Wtile[kk][og * 4 + 0]);
      float4 w1 = *(const float4*)(&Wtile[kk][og * 4 + 64]);
      float4 w2 = *(const float4*)(&Wtile[kk][og * 4 + 128]);
      float4 w3 = *(const float4*)(&Wtile[kk][og * 4 + 192]);
      float b[4] = {bv.x, bv.y, bv.z, bv.w};
#pragma unroll
      for (int j = 0; j < 4; ++j) {
        acc[j][0]  += b[j] * w0.x; acc[j][1]  += b[j] * w0.y;
        acc[j][2]  += b[j] * w0.z; acc[j][3]  += b[j] * w0.w;
        acc[j][4]  += b[j] * w1.x; acc[j][5]  += b[j] * w1.y;
        acc[j][6]  += b[j] * w1.z; acc[j][7]  += b[j] * w1.w;
        acc[j][8]  += b[j] * w2.x; acc[j][9]  += b[j] * w2.y;
        acc[j][10] += b[j] * w2.z; acc[j][11] += b[j] * w2.w;
        acc[j][12] += b[j] * w3.x; acc[j][13] += b[j] * w3.y;
        acc[j][14] += b[j] * w3.z; acc[j][15] += b[j] * w3.w;
      }
    }
  }
#pragma unroll
  for (int j = 0; j < 4; ++j) {
    int gn = block0 + ng * 4 + j;
    if (gn < NN) {
      float* base = proj + (size_t)gn * O2 + og * 4;
      *(float4*)(base + 0)   = make_float4(acc[j][0],  acc[j][1],  acc[j][2],  acc[j][3]);
      *(float4*)(base + 64)  = make_float4(acc[j][4],  acc[j][5],  acc[j][6],  acc[j][7]);
      *(float4*)(base + 128) = make_float4(acc[j][8],  acc[j][9],  acc[j][10], acc[j][11]);
      *(float4*)(base + 192) = make_float4(acc[j][12], acc[j][13], acc[j][14], acc[j][15]);
    }
  }
}

// Wave-per-edge: attn scores -> exp (no max shift: cancels in alpha) -> denom
__global__ __launch_bounds__(256) void edge_attn_kernel(
    const float* __restrict__ proj, const int* __restrict__ ei,
    const float* __restrict__ av, float* __restrict__ p,
    float* __restrict__ denom) {
  int e = blockIdx.x * 4 + (threadIdx.x >> 6);
  if (e >= EE) return;
  int lane = threadIdx.x & 63;
  int s = ei[e];
  int d = ei[EE + e];
  const float* sps = proj + (size_t)s * O2;
  const float* dps = proj + (size_t)d * O2 + 128;
  float a1 = av[lane], a2 = av[64 + lane];
  float v1 = sps[lane] + dps[lane];
  float v2 = sps[64 + lane] + dps[64 + lane];
  v1 = (v1 >= 0.f) ? v1 : 0.2f * v1;  // leaky relu
  v2 = (v2 >= 0.f) ? v2 : 0.2f * v2;
  v1 *= a1;
  v2 *= a2;
#pragma unroll
  for (int off = 1; off < 32; off <<= 1) {  // reduce within 32-lane groups
    v1 += __shfl_xor(v1, off, 64);
    v2 += __shfl_xor(v2, off, 64);
  }
  if ((lane & 31) == 0) {
    int h = lane >> 5;  // 0 or 1
    float p1 = expf(v1), p2 = expf(v2);
    p[(size_t)e * 4 + h] = p1;
    p[(size_t)e * 4 + 2 + h] = p2;
    atomicAdd(&denom[(size_t)d * 4 + h], p1);
    atomicAdd(&denom[(size_t)d * 4 + 2 + h], p2);
  }
}

// Wave-per-edge: alpha = p/denom; scatter sp[src]*alpha into agg (=d_out)
__global__ __launch_bounds__(256) void edge_aggr_kernel(
    const float* __restrict__ proj, const int* __restrict__ ei,
    const float* __restrict__ p, const float* __restrict__ denom,
    float* __restrict__ agg) {
  int e = blockIdx.x * 4 + (threadIdx.x >> 6);
  if (e >= EE) return;
  int lane = threadIdx.x & 63;
  int s = ei[e];
  int d = ei[EE + e];
  int h1 = lane >> 5;
  float alpha1 = p[(size_t)e * 4 + h1] / (denom[(size_t)d * 4 + h1] + 1e-16f);
  float alpha2 = p[(size_t)e * 4 + 2 + h1] / (denom[(size_t)d * 4 + 2 + h1] + 1e-16f);
  const float* sps = proj + (size_t)s * O2;
  atomicAdd(&agg[(size_t)d * 128 + lane], sps[lane] * alpha1);
  atomicAdd(&agg[(size_t)d * 128 + 64 + lane], sps[64 + lane] * alpha2);
}

// Residual + bias + PReLU, in-place on d_out
__global__ __launch_bounds__(256) void finalize_kernel(
    const float* __restrict__ x, const float* __restrict__ bias,
    const float* __restrict__ pa, float* __restrict__ out) {
  int i = blockIdx.x * 256 + threadIdx.x;
  if (i >= NN * FF) return;
  float v = out[i] + x[i] + bias[i & 127];
  float a = pa[0];
  out[i] = (v >= 0.f) ? v : a * v;
}

extern "C" void kernel_launch(void* const* d_in, const int* in_sizes, int n_in,
                              void* d_out, int out_size, void* d_ws, size_t ws_size,
                              hipStream_t stream) {
  const float* x = (const float*)d_in[0];
  const int* ei = (const int*)d_in[1];
  const float* bws = (const float*)d_in[2];
  const float* sws = (const float*)d_in[3];
  const float* bwd = (const float*)d_in[4];
  const float* swd = (const float*)d_in[5];
  const float* av = (const float*)d_in[6];
  const float* bias = (const float*)d_in[7];
  const float* pa = (const float*)d_in[8];

  // ws layout (floats): Wt[393216] | proj[50000*256] | p[800000*4] | denom[50000*4]
  float* Wt = (float*)d_ws;
  float* proj = Wt + (size_t)FF * CHN * O2;
  float* p = proj + (size_t)NN * O2;
  float* denom = p + (size_t)EE * 4;

  hipMemsetAsync(denom, 0, (size_t)NN * 4 * sizeof(float), stream);
  hipMemsetAsync(d_out, 0, (size_t)out_size * sizeof(float), stream);

  repack_kernel<<<(FF * CHN * O2 + 255) / 256, 256, 0, stream>>>(bws, sws, bwd, swd, Wt);
  proj_kernel<<<(NN + 63) / 64, 256, 0, stream>>>(x, Wt, proj);
  edge_attn_kernel<<<EE / 4, 256, 0, stream>>>(proj, ei, av, p, denom);
  edge_aggr_kernel<<<EE / 4, 256, 0, stream>>>(proj, ei, p, denom, (float*)d_out);
  finalize_kernel<<<(NN * FF + 255) / 256, 256, 0, stream>>>(x, bias, pa, (float*)d_out);
}

// Round 3
// 931.862 us; speedup vs baseline: 1.5949x; 1.2685x over previous
//
#include <hip/hip_runtime.h>
#include <math.h>

// Problem constants (match reference)
#define NN 50000   // nodes
#define EE 800000  // edges
#define FF 128     // node features
#define CC 11      // spline coeffs per feature (G+K)
#define O2 256     // combined outputs: 128 src-proj + 128 dst-proj
#define KP 2048    // padded K: 128 features x 16 slots (11 spline + silu + 4 zero)

typedef __attribute__((ext_vector_type(8))) short short8;
typedef __attribute__((ext_vector_type(4))) float f32x4;
typedef unsigned int uint;
typedef unsigned short ushort;

// grid point i (i = 0..14): uniform grid on [-1,1] extended by K=3, h=0.25
__device__ __forceinline__ float gpt(int i) { return 0.25f * (float)i - 1.75f; }

// Cox-de Boor K=3 bases (11 values) + silu(x) as channel 11
__device__ __forceinline__ void kan_basis(float xv, float* out) {
  float b[14];
#pragma unroll
  for (int i = 0; i < 14; ++i)
    b[i] = (xv >= gpt(i) && xv < gpt(i + 1)) ? 1.0f : 0.0f;
#pragma unroll
  for (int j = 1; j <= 3; ++j) {
    float inv = 1.0f / (0.25f * (float)j);
#pragma unroll
    for (int i = 0; i + j < 14; ++i)
      b[i] = (xv - gpt(i)) * inv * b[i] + (gpt(i + j + 1) - xv) * inv * b[i + 1];
  }
#pragma unroll
  for (int c = 0; c < 11; ++c) out[c] = b[c];
  out[11] = xv / (1.0f + expf(-xv));  // silu
}

__device__ __forceinline__ ushort bf16_rne(float v) {
  uint u = __float_as_uint(v);
  u = u + 0x7FFFu + ((u >> 16) & 1u);
  return (ushort)(u >> 16);
}

// Repack weights to B^T layout [o2][k'] (k contiguous), split hi/lo bf16.
// k' = f*16 + ch; ch 0..10 = spline coeff, ch 11 = base (silu) weight, 12..15 = 0
__global__ __launch_bounds__(256) void repack_kernel(
    const float* __restrict__ bws, const float* __restrict__ sws,
    const float* __restrict__ bwd, const float* __restrict__ swd,
    ushort* __restrict__ Wh, ushort* __restrict__ Wl) {
  int idx = blockIdx.x * 256 + threadIdx.x;
  if (idx >= O2 * KP) return;
  int col = idx >> 11;      // 0..255
  int kk = idx & (KP - 1);  // 0..2047
  int f = kk >> 4;
  int ch = kk & 15;
  const float* bw = (col < 128) ? bws : bwd;
  const float* sw = (col < 128) ? sws : swd;
  int o = col & 127;
  float v;
  if (ch < 11)       v = sw[((size_t)o * FF + f) * CC + ch];
  else if (ch == 11) v = bw[(size_t)o * FF + f];
  else               v = 0.f;
  ushort h = bf16_rne(v);
  float hf = __uint_as_float(((uint)h) << 16);
  ushort l = bf16_rne(v - hf);
  Wh[idx] = h;
  Wl[idx] = l;
}

// MFMA KAN projection GEMM (m97 gemm_bt structure):
// block = 64 nodes x 256 cols, 4 waves; wave w -> cols [w*64, w*64+64).
// A tile (basis, bf16-hi) staged in LDS per K-chunk of 32 (= 2 features);
// B fragments (W hi/lo) loaded directly from L2-resident repacked table.
__global__ __launch_bounds__(256) void proj_mfma_kernel(
    const float* __restrict__ x, const ushort* __restrict__ Wh,
    const ushort* __restrict__ Wl, float* __restrict__ proj) {
  __shared__ ushort Ah[64][40];  // k padded 32->40: 80 B row stride, 16B-aligned
  const int t = threadIdx.x;
  const int lane = t & 63;
  const int w = t >> 6;      // wave 0..3
  const int m = lane & 15;
  const int quad = lane >> 4;
  const int block0 = blockIdx.x * 64;

  f32x4 acc[4][4];
#pragma unroll
  for (int r = 0; r < 4; ++r)
#pragma unroll
    for (int c = 0; c < 4; ++c) acc[r][c] = (f32x4)(0.f);

  for (int kc = 0; kc < 64; ++kc) {
    __syncthreads();
    if (t < 128) {  // stage basis for 2 features x 64 nodes, bf16
      int fi = t >> 6;
      int node = t & 63;
      int f = kc * 2 + fi;
      int gn = block0 + node;
      float xv = (gn < NN) ? x[(size_t)gn * FF + f] : 0.f;
      float vals[12];
      kan_basis(xv, vals);
      uint pk[6];
#pragma unroll
      for (int c = 0; c < 6; ++c)
        pk[c] = (uint)bf16_rne(vals[2 * c]) | ((uint)bf16_rne(vals[2 * c + 1]) << 16);
      uint4* dst = (uint4*)&Ah[node][fi * 16];
      dst[0] = make_uint4(pk[0], pk[1], pk[2], pk[3]);
      dst[1] = make_uint4(pk[4], pk[5], 0u, 0u);
    }
    __syncthreads();
    const int k = kc * 32 + quad * 8;
    short8 bh[4], bl[4];
#pragma unroll
    for (int c = 0; c < 4; ++c) {
      size_t off = (size_t)(w * 64 + c * 16 + m) * KP + k;
      bh[c] = *(const short8*)(Wh + off);
      bl[c] = *(const short8*)(Wl + off);
    }
    short8 a[4];
#pragma unroll
    for (int r = 0; r < 4; ++r)
      a[r] = *(const short8*)(&Ah[r * 16 + m][quad * 8]);
#pragma unroll
    for (int r = 0; r < 4; ++r)
#pragma unroll
      for (int c = 0; c < 4; ++c) {
        acc[r][c] = __builtin_amdgcn_mfma_f32_16x16x32_bf16(a[r], bl[c], acc[r][c], 0, 0, 0);
        acc[r][c] = __builtin_amdgcn_mfma_f32_16x16x32_bf16(a[r], bh[c], acc[r][c], 0, 0, 0);
      }
  }
  // epilogue: C/D layout col=lane&15, row=quad*4+reg (verified m89/m91)
#pragma unroll
  for (int r = 0; r < 4; ++r) {
#pragma unroll
    for (int reg = 0; reg < 4; ++reg) {
      int node = block0 + r * 16 + quad * 4 + reg;
      if (node < NN) {
#pragma unroll
        for (int c = 0; c < 4; ++c) {
          int col = w * 64 + c * 16 + m;
          proj[(size_t)node * O2 + col] = acc[r][c][reg];
        }
      }
    }
  }
}

// Wave-per-edge: attn scores -> exp (no max shift: cancels in alpha) -> denom
__global__ __launch_bounds__(256) void edge_attn_kernel(
    const float* __restrict__ proj, const int* __restrict__ ei,
    const float* __restrict__ av, float* __restrict__ p,
    float* __restrict__ denom) {
  int e = blockIdx.x * 4 + (threadIdx.x >> 6);
  if (e >= EE) return;
  int lane = threadIdx.x & 63;
  int s = ei[e];
  int d = ei[EE + e];
  const float* sps = proj + (size_t)s * O2;
  const float* dps = proj + (size_t)d * O2 + 128;
  float a1 = av[lane], a2 = av[64 + lane];
  float v1 = sps[lane] + dps[lane];
  float v2 = sps[64 + lane] + dps[64 + lane];
  v1 = (v1 >= 0.f) ? v1 : 0.2f * v1;  // leaky relu
  v2 = (v2 >= 0.f) ? v2 : 0.2f * v2;
  v1 *= a1;
  v2 *= a2;
#pragma unroll
  for (int off = 1; off < 32; off <<= 1) {  // reduce within 32-lane groups
    v1 += __shfl_xor(v1, off, 64);
    v2 += __shfl_xor(v2, off, 64);
  }
  if ((lane & 31) == 0) {
    int h = lane >> 5;  // 0 or 1
    float p1 = expf(v1), p2 = expf(v2);
    p[(size_t)e * 4 + h] = p1;
    p[(size_t)e * 4 + 2 + h] = p2;
    atomicAdd(&denom[(size_t)d * 4 + h], p1);
    atomicAdd(&denom[(size_t)d * 4 + 2 + h], p2);
  }
}

// Wave-per-edge: alpha = p/denom; scatter sp[src]*alpha into agg (=d_out)
__global__ __launch_bounds__(256) void edge_aggr_kernel(
    const float* __restrict__ proj, const int* __restrict__ ei,
    const float* __restrict__ p, const float* __restrict__ denom,
    float* __restrict__ agg) {
  int e = blockIdx.x * 4 + (threadIdx.x >> 6);
  if (e >= EE) return;
  int lane = threadIdx.x & 63;
  int s = ei[e];
  int d = ei[EE + e];
  int h1 = lane >> 5;
  float alpha1 = p[(size_t)e * 4 + h1] / (denom[(size_t)d * 4 + h1] + 1e-16f);
  float alpha2 = p[(size_t)e * 4 + 2 + h1] / (denom[(size_t)d * 4 + 2 + h1] + 1e-16f);
  const float* sps = proj + (size_t)s * O2;
  atomicAdd(&agg[(size_t)d * 128 + lane], sps[lane] * alpha1);
  atomicAdd(&agg[(size_t)d * 128 + 64 + lane], sps[64 + lane] * alpha2);
}

// Residual + bias + PReLU, in-place on d_out
__global__ __launch_bounds__(256) void finalize_kernel(
    const float* __restrict__ x, const float* __restrict__ bias,
    const float* __restrict__ pa, float* __restrict__ out) {
  int i = blockIdx.x * 256 + threadIdx.x;
  if (i >= NN * FF) return;
  float v = out[i] + x[i] + bias[i & 127];
  float a = pa[0];
  out[i] = (v >= 0.f) ? v : a * v;
}

extern "C" void kernel_launch(void* const* d_in, const int* in_sizes, int n_in,
                              void* d_out, int out_size, void* d_ws, size_t ws_size,
                              hipStream_t stream) {
  const float* x = (const float*)d_in[0];
  const int* ei = (const int*)d_in[1];
  const float* bws = (const float*)d_in[2];
  const float* sws = (const float*)d_in[3];
  const float* bwd = (const float*)d_in[4];
  const float* swd = (const float*)d_in[5];
  const float* av = (const float*)d_in[6];
  const float* bias = (const float*)d_in[7];
  const float* pa = (const float*)d_in[8];

  // ws layout: Wh[524288 u16] | Wl[524288 u16] | proj[12.8M f32] | p[3.2M f32] | denom[0.2M f32]
  ushort* Wh = (ushort*)d_ws;
  ushort* Wl = Wh + (size_t)O2 * KP;
  float* proj = (float*)(Wl + (size_t)O2 * KP);
  float* p = proj + (size_t)NN * O2;
  float* denom = p + (size_t)EE * 4;

  hipMemsetAsync(denom, 0, (size_t)NN * 4 * sizeof(float), stream);
  hipMemsetAsync(d_out, 0, (size_t)out_size * sizeof(float), stream);

  repack_kernel<<<(O2 * KP + 255) / 256, 256, 0, stream>>>(bws, sws, bwd, swd, Wh, Wl);
  proj_mfma_kernel<<<(NN + 63) / 64, 256, 0, stream>>>(x, Wh, Wl, proj);
  edge_attn_kernel<<<EE / 4, 256, 0, stream>>>(proj, ei, av, p, denom);
  edge_aggr_kernel<<<EE / 4, 256, 0, stream>>>(proj, ei, p, denom, (float*)d_out);
  finalize_kernel<<<(NN * FF + 255) / 256, 256, 0, stream>>>(x, bias, pa, (float*)d_out);
}

// Round 4
// 575.691 us; speedup vs baseline: 2.5816x; 1.6187x over previous
//
#include <hip/hip_runtime.h>
#include <math.h>

// Problem constants (match reference)
#define NN 50000   // nodes
#define EE 800000  // edges
#define FF 128     // node features
#define CC 11      // spline coeffs per feature (G+K)
#define O2 256     // combined outputs: 128 src-proj + 128 dst-proj
#define KP 2048    // padded K: 128 features x 16 slots (11 spline + silu + 4 zero)
#define BK 256     // K-chunk: 16 features
#define NKC 8      // KP / BK
#define LDSROW 264 // A-tile row in shorts (256 + 8 pad): stride 528 B = 132 dwords = 4 mod 32 banks

typedef __attribute__((ext_vector_type(8))) short short8;
typedef __attribute__((ext_vector_type(4))) float f32x4;
typedef unsigned int uint;
typedef unsigned short ushort;

// grid point i (i = 0..14): uniform grid on [-1,1] extended by K=3, h=0.25
__device__ __forceinline__ float gpt(int i) { return 0.25f * (float)i - 1.75f; }

// Cox-de Boor K=3 bases (11 values) + silu(x) as channel 11
__device__ __forceinline__ void kan_basis(float xv, float* out) {
  float b[14];
#pragma unroll
  for (int i = 0; i < 14; ++i)
    b[i] = (xv >= gpt(i) && xv < gpt(i + 1)) ? 1.0f : 0.0f;
#pragma unroll
  for (int j = 1; j <= 3; ++j) {
    float inv = 1.0f / (0.25f * (float)j);
#pragma unroll
    for (int i = 0; i + j < 14; ++i)
      b[i] = (xv - gpt(i)) * inv * b[i] + (gpt(i + j + 1) - xv) * inv * b[i + 1];
  }
#pragma unroll
  for (int c = 0; c < 11; ++c) out[c] = b[c];
  out[11] = xv / (1.0f + expf(-xv));  // silu
}

__device__ __forceinline__ ushort bf16_rne(float v) {
  uint u = __float_as_uint(v);
  u = u + 0x7FFFu + ((u >> 16) & 1u);
  return (ushort)(u >> 16);
}

// Repack weights to B^T layout [o2][k'] (k contiguous), split hi/lo bf16.
// k' = f*16 + ch; ch 0..10 = spline coeff, ch 11 = base (silu) weight, 12..15 = 0
__global__ __launch_bounds__(256) void repack_kernel(
    const float* __restrict__ bws, const float* __restrict__ sws,
    const float* __restrict__ bwd, const float* __restrict__ swd,
    ushort* __restrict__ Wh, ushort* __restrict__ Wl) {
  int idx = blockIdx.x * 256 + threadIdx.x;
  if (idx >= O2 * KP) return;
  int col = idx >> 11;      // 0..255
  int kk = idx & (KP - 1);  // 0..2047
  int f = kk >> 4;
  int ch = kk & 15;
  const float* bw = (col < 128) ? bws : bwd;
  const float* sw = (col < 128) ? sws : swd;
  int o = col & 127;
  float v;
  if (ch < 11)       v = sw[((size_t)o * FF + f) * CC + ch];
  else if (ch == 11) v = bw[(size_t)o * FF + f];
  else               v = 0.f;
  ushort h = bf16_rne(v);
  float hf = __uint_as_float(((uint)h) << 16);
  ushort l = bf16_rne(v - hf);
  Wh[idx] = h;
  Wl[idx] = l;
}

// MFMA KAN projection GEMM. Block = 64 nodes x 256 cols, 4 waves.
// K chunked by 256 (16 features): all 256 threads compute basis (4 kan_basis
// each from one float4 x-load), then a barrier-free 8-step MFMA sub-loop with
// B (hi/lo) streamed from the L2-resident repacked table.
__global__ __launch_bounds__(256) void proj_mfma_kernel(
    const float* __restrict__ x, const ushort* __restrict__ Wh,
    const ushort* __restrict__ Wl, float* __restrict__ proj) {
  __shared__ ushort Ah[64][LDSROW];  // 33.8 KB
  const int t = threadIdx.x;
  const int lane = t & 63;
  const int w = t >> 6;      // wave 0..3
  const int m = lane & 15;
  const int quad = lane >> 4;
  const int block0 = blockIdx.x * 64;
  const int gn = block0 + lane;  // staging: node = lane, feature group = wave

  f32x4 acc[4][4];
#pragma unroll
  for (int r = 0; r < 4; ++r)
#pragma unroll
    for (int c = 0; c < 4; ++c) acc[r][c] = (f32x4)(0.f);

  for (int kc = 0; kc < NKC; ++kc) {
    __syncthreads();
    {  // stage basis for 16 features x 64 nodes (4 features per thread)
      float4 xv = make_float4(0.f, 0.f, 0.f, 0.f);
      if (gn < NN) xv = *(const float4*)(x + (size_t)gn * FF + kc * 16 + w * 4);
      float xa[4] = {xv.x, xv.y, xv.z, xv.w};
#pragma unroll
      for (int j = 0; j < 4; ++j) {
        float vals[12];
        kan_basis(xa[j], vals);
        uint pk[6];
#pragma unroll
        for (int c = 0; c < 6; ++c)
          pk[c] = (uint)bf16_rne(vals[2 * c]) | ((uint)bf16_rne(vals[2 * c + 1]) << 16);
        uint4* dst = (uint4*)&Ah[lane][(w * 4 + j) * 16];
        dst[0] = make_uint4(pk[0], pk[1], pk[2], pk[3]);
        dst[1] = make_uint4(pk[4], pk[5], 0u, 0u);
      }
    }
    __syncthreads();
#pragma unroll
    for (int sk = 0; sk < 8; ++sk) {
      const int kg = kc * BK + sk * 32 + quad * 8;
      short8 bh[4], bl[4], a[4];
#pragma unroll
      for (int c = 0; c < 4; ++c) {
        size_t off = (size_t)(w * 64 + c * 16 + m) * KP + kg;
        bh[c] = *(const short8*)(Wh + off);
        bl[c] = *(const short8*)(Wl + off);
      }
#pragma unroll
      for (int r = 0; r < 4; ++r)
        a[r] = *(const short8*)(&Ah[r * 16 + m][sk * 32 + quad * 8]);
#pragma unroll
      for (int r = 0; r < 4; ++r)
#pragma unroll
        for (int c = 0; c < 4; ++c) {
          acc[r][c] = __builtin_amdgcn_mfma_f32_16x16x32_bf16(a[r], bl[c], acc[r][c], 0, 0, 0);
          acc[r][c] = __builtin_amdgcn_mfma_f32_16x16x32_bf16(a[r], bh[c], acc[r][c], 0, 0, 0);
        }
    }
  }
  // epilogue: C/D layout col=lane&15, row=quad*4+reg (verified m89/m91)
#pragma unroll
  for (int r = 0; r < 4; ++r) {
#pragma unroll
    for (int reg = 0; reg < 4; ++reg) {
      int node = block0 + r * 16 + quad * 4 + reg;
      if (node < NN) {
#pragma unroll
        for (int c = 0; c < 4; ++c) {
          int col = w * 64 + c * 16 + m;
          proj[(size_t)node * O2 + col] = acc[r][c][reg];
        }
      }
    }
  }
}

// ---- CSR build ----
__global__ __launch_bounds__(256) void count_kernel(
    const int* __restrict__ ei, int* __restrict__ deg) {
  int e = blockIdx.x * 256 + threadIdx.x;
  if (e < EE) atomicAdd(&deg[ei[EE + e]], 1);
}

// block-level exclusive scan; ex[idx] = excl within block, partial[b] = block sum
__global__ __launch_bounds__(256) void scanA_kernel(
    const int* __restrict__ deg, int* __restrict__ ex, int* __restrict__ partial) {
  __shared__ int sd[256];
  int t = threadIdx.x;
  int idx = blockIdx.x * 256 + t;
  int v = (idx < NN) ? deg[idx] : 0;
  sd[t] = v;
  __syncthreads();
#pragma unroll
  for (int off = 1; off < 256; off <<= 1) {
    int add = (t >= off) ? sd[t - off] : 0;
    __syncthreads();
    sd[t] += add;
    __syncthreads();
  }
  if (idx < NN) ex[idx] = sd[t] - v;
  if (t == 255) partial[blockIdx.x] = sd[255];
}

// single-block exclusive scan of block partials
__global__ __launch_bounds__(256) void scanB_kernel(
    const int* __restrict__ partial, int* __restrict__ poff, int nblk) {
  __shared__ int sd[256];
  int t = threadIdx.x;
  int v = (t < nblk) ? partial[t] : 0;
  sd[t] = v;
  __syncthreads();
#pragma unroll
  for (int off = 1; off < 256; off <<= 1) {
    int add = (t >= off) ? sd[t - off] : 0;
    __syncthreads();
    sd[t] += add;
    __syncthreads();
  }
  if (t < nblk) poff[t] = sd[t] - v;
}

__global__ __launch_bounds__(256) void scanC_kernel(
    const int* __restrict__ ex, const int* __restrict__ poff,
    int* __restrict__ row_ptr) {
  int idx = blockIdx.x * 256 + threadIdx.x;
  if (idx < NN) row_ptr[idx] = ex[idx] + poff[idx >> 8];
  if (idx == 0) row_ptr[NN] = EE;
}

__global__ __launch_bounds__(256) void fill_kernel(
    const int* __restrict__ ei, const int* __restrict__ row_ptr,
    int* __restrict__ cur, int* __restrict__ ebucket) {
  int e = blockIdx.x * 256 + threadIdx.x;
  if (e >= EE) return;
  int d = ei[EE + e];
  int pos = row_ptr[d] + atomicAdd(&cur[d], 1);
  ebucket[pos] = e;
}

// Fused per-dst aggregation: one wave per dst node, single pass over in-edges.
// Online softmax (no max shift: cancels in alpha), no atomics, fused epilogue.
__global__ __launch_bounds__(256) void aggr_kernel(
    const float* __restrict__ proj, const int* __restrict__ ei,
    const int* __restrict__ ebucket, const int* __restrict__ row_ptr,
    const float* __restrict__ av, const float* __restrict__ x,
    const float* __restrict__ bias, const float* __restrict__ pa,
    float* __restrict__ out) {
  int d = blockIdx.x * 4 + (threadIdx.x >> 6);
  if (d >= NN) return;
  int l = threadIdx.x & 63;
  float dpv1 = proj[(size_t)d * O2 + 128 + l];
  float dpv2 = proj[(size_t)d * O2 + 192 + l];
  float av1 = av[l], av2 = av[64 + l];
  int i0 = row_ptr[d], i1 = row_ptr[d + 1];
  float acc1 = 0.f, acc2 = 0.f, den1 = 0.f, den2 = 0.f;
  for (int i = i0; i < i1; ++i) {
    int s = ei[ebucket[i]];
    float sp1 = proj[(size_t)s * O2 + l];
    float sp2 = proj[(size_t)s * O2 + 64 + l];
    float v1 = sp1 + dpv1;
    float v2 = sp2 + dpv2;
    v1 = (v1 >= 0.f) ? v1 : 0.2f * v1;
    v2 = (v2 >= 0.f) ? v2 : 0.2f * v2;
    v1 *= av1;
    v2 *= av2;
#pragma unroll
    for (int off = 1; off < 32; off <<= 1) {  // per-head sums (32-lane groups)
      v1 += __shfl_xor(v1, off, 64);
      v2 += __shfl_xor(v2, off, 64);
    }
    float e1 = expf(v1), e2 = expf(v2);
    acc1 += e1 * sp1;
    den1 += e1;
    acc2 += e2 * sp2;
    den2 += e2;
  }
  float a = pa[0];
  float o1 = acc1 / (den1 + 1e-16f) + x[(size_t)d * FF + l] + bias[l];
  float o2 = acc2 / (den2 + 1e-16f) + x[(size_t)d * FF + 64 + l] + bias[64 + l];
  out[(size_t)d * FF + l] = (o1 >= 0.f) ? o1 : a * o1;
  out[(size_t)d * FF + 64 + l] = (o2 >= 0.f) ? o2 : a * o2;
}

extern "C" void kernel_launch(void* const* d_in, const int* in_sizes, int n_in,
                              void* d_out, int out_size, void* d_ws, size_t ws_size,
                              hipStream_t stream) {
  const float* x = (const float*)d_in[0];
  const int* ei = (const int*)d_in[1];
  const float* bws = (const float*)d_in[2];
  const float* sws = (const float*)d_in[3];
  const float* bwd = (const float*)d_in[4];
  const float* swd = (const float*)d_in[5];
  const float* av = (const float*)d_in[6];
  const float* bias = (const float*)d_in[7];
  const float* pa = (const float*)d_in[8];

  // ws layout: Wh | Wl | proj | deg | ex | cur | row_ptr | partial | poff | ebucket
  ushort* Wh = (ushort*)d_ws;
  ushort* Wl = Wh + (size_t)O2 * KP;
  float* proj = (float*)(Wl + (size_t)O2 * KP);
  int* deg = (int*)(proj + (size_t)NN * O2);
  int* ex = deg + NN;
  int* cur = ex + NN;
  int* row_ptr = cur + NN;         // NN+1 entries
  int* partial = row_ptr + NN + 1;
  int* poff = partial + 256;
  int* ebucket = poff + 256;

  const int NB = (NN + 255) / 256;  // 196 scan blocks

  hipMemsetAsync(deg, 0, (size_t)NN * sizeof(int), stream);
  hipMemsetAsync(cur, 0, (size_t)NN * sizeof(int), stream);

  repack_kernel<<<(O2 * KP + 255) / 256, 256, 0, stream>>>(bws, sws, bwd, swd, Wh, Wl);
  proj_mfma_kernel<<<(NN + 63) / 64, 256, 0, stream>>>(x, Wh, Wl, proj);
  count_kernel<<<(EE + 255) / 256, 256, 0, stream>>>(ei, deg);
  scanA_kernel<<<NB, 256, 0, stream>>>(deg, ex, partial);
  scanB_kernel<<<1, 256, 0, stream>>>(partial, poff, NB);
  scanC_kernel<<<NB, 256, 0, stream>>>(ex, poff, row_ptr);
  fill_kernel<<<(EE + 255) / 256, 256, 0, stream>>>(ei, row_ptr, cur, ebucket);
  aggr_kernel<<<(NN + 3) / 4, 256, 0, stream>>>(proj, ei, ebucket, row_ptr, av, x, bias, pa,
                                                (float*)d_out);
}

// Round 5
// 405.924 us; speedup vs baseline: 3.6612x; 1.4182x over previous
//
#include <hip/hip_runtime.h>
#include <math.h>

// Problem constants (match reference)
#define NN 50000   // nodes
#define EE 800000  // edges
#define FF 128     // node features
#define CC 11      // spline coeffs per feature (G+K)
#define O2 256     // combined outputs: 128 src-proj + 128 dst-proj
#define KT 1536    // true K: 128 features x 12 slots (11 spline + silu)
#define NKC 8      // K-chunks of 192 (16 features x 12)
#define LDSROW 200 // A-tile row in shorts (192 + 8 pad): 400 B = 100 dw = 4 mod 32 banks (2-way, free)

typedef __attribute__((ext_vector_type(8))) short short8;
typedef __attribute__((ext_vector_type(4))) float f32x4;
typedef unsigned int uint;
typedef unsigned short ushort;

// grid point i (i = 0..14): uniform grid on [-1,1] extended by K=3, h=0.25
__device__ __forceinline__ float gpt(int i) { return 0.25f * (float)i - 1.75f; }

// Cox-de Boor K=3 bases (11 values) + silu(x) as channel 11
__device__ __forceinline__ void kan_basis(float xv, float* out) {
  float b[14];
#pragma unroll
  for (int i = 0; i < 14; ++i)
    b[i] = (xv >= gpt(i) && xv < gpt(i + 1)) ? 1.0f : 0.0f;
#pragma unroll
  for (int j = 1; j <= 3; ++j) {
    float inv = 1.0f / (0.25f * (float)j);
#pragma unroll
    for (int i = 0; i + j < 14; ++i)
      b[i] = (xv - gpt(i)) * inv * b[i] + (gpt(i + j + 1) - xv) * inv * b[i + 1];
  }
#pragma unroll
  for (int c = 0; c < 11; ++c) out[c] = b[c];
  out[11] = xv / (1.0f + expf(-xv));  // silu
}

__device__ __forceinline__ ushort bf16_rne(float v) {
  uint u = __float_as_uint(v);
  u = u + 0x7FFFu + ((u >> 16) & 1u);
  return (ushort)(u >> 16);
}

// Repack weights to B^T layout [o2][k] (k contiguous), bf16.
// k = f*12 + ch; ch 0..10 = spline coeff, ch 11 = base (silu) weight
__global__ __launch_bounds__(256) void repack_kernel(
    const float* __restrict__ bws, const float* __restrict__ sws,
    const float* __restrict__ bwd, const float* __restrict__ swd,
    ushort* __restrict__ Wh) {
  int idx = blockIdx.x * 256 + threadIdx.x;
  if (idx >= O2 * KT) return;
  int col = idx / KT;
  int kk = idx - col * KT;
  int f = kk / 12;
  int ch = kk - f * 12;
  const float* bw = (col < 128) ? bws : bwd;
  const float* sw = (col < 128) ? sws : swd;
  int o = col & 127;
  float v = (ch == 11) ? bw[(size_t)o * FF + f] : sw[((size_t)o * FF + f) * CC + ch];
  Wh[idx] = bf16_rne(v);
}

// MFMA KAN projection GEMM. Block = 64 nodes x 256 cols, 4 waves.
// K = 1536, chunked by 192 (16 features x 12 slots): all 256 threads compute
// basis (4 kan_basis each from one float4 x-load), then a barrier-free 6-step
// MFMA sub-loop with B streamed bf16 from the L2-resident repacked table.
__global__ __launch_bounds__(256) void proj_mfma_kernel(
    const float* __restrict__ x, const ushort* __restrict__ Wh,
    float* __restrict__ proj) {
  __shared__ ushort Ah[64][LDSROW];  // 25.6 KB
  const int t = threadIdx.x;
  const int lane = t & 63;
  const int w = t >> 6;      // wave 0..3
  const int m = lane & 15;
  const int quad = lane >> 4;
  const int block0 = blockIdx.x * 64;
  const int gn = block0 + lane;  // staging: node = lane, feature group = wave

  f32x4 acc[4][4];
#pragma unroll
  for (int r = 0; r < 4; ++r)
#pragma unroll
    for (int c = 0; c < 4; ++c) acc[r][c] = (f32x4)(0.f);

  for (int kc = 0; kc < NKC; ++kc) {
    __syncthreads();
    {  // stage basis for 16 features x 64 nodes (4 features per thread, 12 slots each)
      float4 xv = make_float4(0.f, 0.f, 0.f, 0.f);
      if (gn < NN) xv = *(const float4*)(x + (size_t)gn * FF + kc * 16 + w * 4);
      float xa[4] = {xv.x, xv.y, xv.z, xv.w};
      uint pk[24];
#pragma unroll
      for (int j = 0; j < 4; ++j) {
        float vals[12];
        kan_basis(xa[j], vals);
#pragma unroll
        for (int c = 0; c < 6; ++c)
          pk[j * 6 + c] =
              (uint)bf16_rne(vals[2 * c]) | ((uint)bf16_rne(vals[2 * c + 1]) << 16);
      }
      uint4* dst = (uint4*)&Ah[lane][w * 48];  // 96 B per thread, 16B-aligned
#pragma unroll
      for (int i = 0; i < 6; ++i)
        dst[i] = make_uint4(pk[i * 4], pk[i * 4 + 1], pk[i * 4 + 2], pk[i * 4 + 3]);
    }
    __syncthreads();
#pragma unroll
    for (int sk = 0; sk < 6; ++sk) {
      const int kg = kc * 192 + sk * 32 + quad * 8;
      short8 bh[4], a[4];
#pragma unroll
      for (int c = 0; c < 4; ++c)
        bh[c] = *(const short8*)(Wh + (size_t)(w * 64 + c * 16 + m) * KT + kg);
#pragma unroll
      for (int r = 0; r < 4; ++r)
        a[r] = *(const short8*)(&Ah[r * 16 + m][sk * 32 + quad * 8]);
#pragma unroll
      for (int r = 0; r < 4; ++r)
#pragma unroll
        for (int c = 0; c < 4; ++c)
          acc[r][c] = __builtin_amdgcn_mfma_f32_16x16x32_bf16(a[r], bh[c], acc[r][c], 0, 0, 0);
    }
  }
  // epilogue: C/D layout col=lane&15, row=quad*4+reg (verified m89/m91)
#pragma unroll
  for (int r = 0; r < 4; ++r) {
#pragma unroll
    for (int reg = 0; reg < 4; ++reg) {
      int node = block0 + r * 16 + quad * 4 + reg;
      if (node < NN) {
#pragma unroll
        for (int c = 0; c < 4; ++c) {
          int col = w * 64 + c * 16 + m;
          proj[(size_t)node * O2 + col] = acc[r][c][reg];
        }
      }
    }
  }
}

// ---- CSR build ----
__global__ __launch_bounds__(256) void count_kernel(
    const int* __restrict__ ei, int* __restrict__ deg) {
  int e = blockIdx.x * 256 + threadIdx.x;
  if (e < EE) atomicAdd(&deg[ei[EE + e]], 1);
}

// block-level exclusive scan; ex[idx] = excl within block, partial[b] = block sum
__global__ __launch_bounds__(256) void scanA_kernel(
    const int* __restrict__ deg, int* __restrict__ ex, int* __restrict__ partial) {
  __shared__ int sd[256];
  int t = threadIdx.x;
  int idx = blockIdx.x * 256 + t;
  int v = (idx < NN) ? deg[idx] : 0;
  sd[t] = v;
  __syncthreads();
#pragma unroll
  for (int off = 1; off < 256; off <<= 1) {
    int add = (t >= off) ? sd[t - off] : 0;
    __syncthreads();
    sd[t] += add;
    __syncthreads();
  }
  if (idx < NN) ex[idx] = sd[t] - v;
  if (t == 255) partial[blockIdx.x] = sd[255];
}

// single-block exclusive scan of block partials
__global__ __launch_bounds__(256) void scanB_kernel(
    const int* __restrict__ partial, int* __restrict__ poff, int nblk) {
  __shared__ int sd[256];
  int t = threadIdx.x;
  int v = (t < nblk) ? partial[t] : 0;
  sd[t] = v;
  __syncthreads();
#pragma unroll
  for (int off = 1; off < 256; off <<= 1) {
    int add = (t >= off) ? sd[t - off] : 0;
    __syncthreads();
    sd[t] += add;
    __syncthreads();
  }
  if (t < nblk) poff[t] = sd[t] - v;
}

__global__ __launch_bounds__(256) void scanC_kernel(
    const int* __restrict__ ex, const int* __restrict__ poff,
    int* __restrict__ row_ptr) {
  int idx = blockIdx.x * 256 + threadIdx.x;
  if (idx < NN) row_ptr[idx] = ex[idx] + poff[idx >> 8];
  if (idx == 0) row_ptr[NN] = EE;
}

// store SRC id directly (no edge-id indirection in aggr)
__global__ __launch_bounds__(256) void fill_kernel(
    const int* __restrict__ ei, const int* __restrict__ row_ptr,
    int* __restrict__ cur, int* __restrict__ scsr) {
  int e = blockIdx.x * 256 + threadIdx.x;
  if (e >= EE) return;
  int s = ei[e];
  int d = ei[EE + e];
  int pos = row_ptr[d] + atomicAdd(&cur[d], 1);
  scsr[pos] = s;
}

// Fused per-dst aggregation: one wave per dst node, single pass over in-edges.
// Online softmax (no max shift: cancels in alpha), no atomics, fused epilogue.
// src index prefetched one iteration ahead.
__global__ __launch_bounds__(256) void aggr_kernel(
    const float* __restrict__ proj, const int* __restrict__ scsr,
    const int* __restrict__ row_ptr, const float* __restrict__ av,
    const float* __restrict__ x, const float* __restrict__ bias,
    const float* __restrict__ pa, float* __restrict__ out) {
  int d = blockIdx.x * 4 + (threadIdx.x >> 6);
  if (d >= NN) return;
  int l = threadIdx.x & 63;
  float dpv1 = proj[(size_t)d * O2 + 128 + l];
  float dpv2 = proj[(size_t)d * O2 + 192 + l];
  float av1 = av[l], av2 = av[64 + l];
  int i0 = row_ptr[d], i1 = row_ptr[d + 1];
  float acc1 = 0.f, acc2 = 0.f, den1 = 0.f, den2 = 0.f;
  int s = (i0 < i1) ? scsr[i0] : 0;
  for (int i = i0; i < i1; ++i) {
    int sn = (i + 1 < i1) ? scsr[i + 1] : 0;
    float sp1 = proj[(size_t)s * O2 + l];
    float sp2 = proj[(size_t)s * O2 + 64 + l];
    float v1 = sp1 + dpv1;
    float v2 = sp2 + dpv2;
    v1 = (v1 >= 0.f) ? v1 : 0.2f * v1;
    v2 = (v2 >= 0.f) ? v2 : 0.2f * v2;
    v1 *= av1;
    v2 *= av2;
#pragma unroll
    for (int off = 1; off < 32; off <<= 1) {  // per-head sums (32-lane groups)
      v1 += __shfl_xor(v1, off, 64);
      v2 += __shfl_xor(v2, off, 64);
    }
    float e1 = expf(v1), e2 = expf(v2);
    acc1 += e1 * sp1;
    den1 += e1;
    acc2 += e2 * sp2;
    den2 += e2;
    s = sn;
  }
  float a = pa[0];
  float o1 = acc1 / (den1 + 1e-16f) + x[(size_t)d * FF + l] + bias[l];
  float o2 = acc2 / (den2 + 1e-16f) + x[(size_t)d * FF + 64 + l] + bias[64 + l];
  out[(size_t)d * FF + l] = (o1 >= 0.f) ? o1 : a * o1;
  out[(size_t)d * FF + 64 + l] = (o2 >= 0.f) ? o2 : a * o2;
}

extern "C" void kernel_launch(void* const* d_in, const int* in_sizes, int n_in,
                              void* d_out, int out_size, void* d_ws, size_t ws_size,
                              hipStream_t stream) {
  const float* x = (const float*)d_in[0];
  const int* ei = (const int*)d_in[1];
  const float* bws = (const float*)d_in[2];
  const float* sws = (const float*)d_in[3];
  const float* bwd = (const float*)d_in[4];
  const float* swd = (const float*)d_in[5];
  const float* av = (const float*)d_in[6];
  const float* bias = (const float*)d_in[7];
  const float* pa = (const float*)d_in[8];

  // ws layout: Wh | proj | deg | ex | cur | row_ptr | partial | poff | scsr
  ushort* Wh = (ushort*)d_ws;
  float* proj = (float*)(Wh + (size_t)O2 * KT);
  int* deg = (int*)(proj + (size_t)NN * O2);
  int* ex = deg + NN;
  int* cur = ex + NN;
  int* row_ptr = cur + NN;         // NN+1 entries
  int* partial = row_ptr + NN + 1;
  int* poff = partial + 256;
  int* scsr = poff + 256;

  const int NB = (NN + 255) / 256;  // 196 scan blocks

  hipMemsetAsync(deg, 0, (size_t)NN * sizeof(int), stream);
  hipMemsetAsync(cur, 0, (size_t)NN * sizeof(int), stream);

  repack_kernel<<<(O2 * KT + 255) / 256, 256, 0, stream>>>(bws, sws, bwd, swd, Wh);
  proj_mfma_kernel<<<(NN + 63) / 64, 256, 0, stream>>>(x, Wh, proj);
  count_kernel<<<(EE + 255) / 256, 256, 0, stream>>>(ei, deg);
  scanA_kernel<<<NB, 256, 0, stream>>>(deg, ex, partial);
  scanB_kernel<<<1, 256, 0, stream>>>(partial, poff, NB);
  scanC_kernel<<<NB, 256, 0, stream>>>(ex, poff, row_ptr);
  fill_kernel<<<(EE + 255) / 256, 256, 0, stream>>>(ei, row_ptr, cur, scsr);
  aggr_kernel<<<(NN + 3) / 4, 256, 0, stream>>>(proj, scsr, row_ptr, av, x, bias, pa,
                                                (float*)d_out);
}

// Round 6
// 396.774 us; speedup vs baseline: 3.7457x; 1.0231x over previous
//
#include <hip/hip_runtime.h>
#include <math.h>

// Problem constants (match reference)
#define NN 50000   // nodes
#define EE 800000  // edges
#define FF 128     // node features
#define CC 11      // spline coeffs per feature (G+K)
#define O2 256     // combined outputs: 128 src-proj + 128 dst-proj
#define KT 1536    // true K: 128 features x 12 slots (11 spline + silu)
#define NKC 8      // K-chunks of 192 (16 features x 12)
#define LDSROW 200 // A-tile row in shorts (192 + 8 pad): 400 B = 100 dw = 4 mod 32 banks (2-way, free)

typedef __attribute__((ext_vector_type(8))) short short8;
typedef __attribute__((ext_vector_type(4))) float f32x4;
typedef unsigned int uint;
typedef unsigned short ushort;

// grid point i (i = 0..14): uniform grid on [-1,1] extended by K=3, h=0.25
__device__ __forceinline__ float gpt(int i) { return 0.25f * (float)i - 1.75f; }

// Cox-de Boor K=3 bases (11 values) + silu(x) as channel 11
__device__ __forceinline__ void kan_basis(float xv, float* out) {
  float b[14];
#pragma unroll
  for (int i = 0; i < 14; ++i)
    b[i] = (xv >= gpt(i) && xv < gpt(i + 1)) ? 1.0f : 0.0f;
#pragma unroll
  for (int j = 1; j <= 3; ++j) {
    float inv = 1.0f / (0.25f * (float)j);
#pragma unroll
    for (int i = 0; i + j < 14; ++i)
      b[i] = (xv - gpt(i)) * inv * b[i] + (gpt(i + j + 1) - xv) * inv * b[i + 1];
  }
#pragma unroll
  for (int c = 0; c < 11; ++c) out[c] = b[c];
  out[11] = xv / (1.0f + __expf(-xv));  // silu
}

__device__ __forceinline__ ushort bf16_rne(float v) {
  uint u = __float_as_uint(v);
  u = u + 0x7FFFu + ((u >> 16) & 1u);
  return (ushort)(u >> 16);
}

// Repack weights to B^T layout [o2][k] (k contiguous), bf16.
// k = f*12 + ch; ch 0..10 = spline coeff, ch 11 = base (silu) weight
__global__ __launch_bounds__(256) void repack_kernel(
    const float* __restrict__ bws, const float* __restrict__ sws,
    const float* __restrict__ bwd, const float* __restrict__ swd,
    ushort* __restrict__ Wh) {
  int idx = blockIdx.x * 256 + threadIdx.x;
  if (idx >= O2 * KT) return;
  int col = idx / KT;
  int kk = idx - col * KT;
  int f = kk / 12;
  int ch = kk - f * 12;
  const float* bw = (col < 128) ? bws : bwd;
  const float* sw = (col < 128) ? sws : swd;
  int o = col & 127;
  float v = (ch == 11) ? bw[(size_t)o * FF + f] : sw[((size_t)o * FF + f) * CC + ch];
  Wh[idx] = bf16_rne(v);
}

// MFMA KAN projection GEMM. Block = 64 nodes x 256 cols, 4 waves.
// Double-buffered A-tile (one barrier/chunk): iteration kc issues sk=0
// B-prefetch, computes chunk kc+1's basis into the other buffer (B-load
// latency hides under basis VALU), then runs the 6-step MFMA sub-loop with
// rolling B prefetch over buffer kc&1.
__global__ __launch_bounds__(256) void proj_mfma_kernel(
    const float* __restrict__ x, const ushort* __restrict__ Wh,
    float* __restrict__ proj) {
  __shared__ ushort Ah[2][64][LDSROW];  // 51.2 KB
  const int t = threadIdx.x;
  const int lane = t & 63;
  const int w = t >> 6;      // wave 0..3
  const int m = lane & 15;
  const int quad = lane >> 4;
  const int block0 = blockIdx.x * 64;
  const int gn = block0 + lane;  // staging: node = lane, feature group = wave
  const bool valid = (gn < NN);

  auto stage = [&](float4 xv, ushort(*buf)[LDSROW]) {
    float xa[4] = {xv.x, xv.y, xv.z, xv.w};
    uint pk[24];
#pragma unroll
    for (int j = 0; j < 4; ++j) {
      float vals[12];
      kan_basis(xa[j], vals);
#pragma unroll
      for (int c = 0; c < 6; ++c)
        pk[j * 6 + c] =
            (uint)bf16_rne(vals[2 * c]) | ((uint)bf16_rne(vals[2 * c + 1]) << 16);
    }
    uint4* dst = (uint4*)&buf[lane][w * 48];  // 96 B per thread, 16B-aligned
#pragma unroll
    for (int i = 0; i < 6; ++i)
      dst[i] = make_uint4(pk[i * 4], pk[i * 4 + 1], pk[i * 4 + 2], pk[i * 4 + 3]);
  };

  f32x4 acc[4][4];
#pragma unroll
  for (int r = 0; r < 4; ++r)
#pragma unroll
    for (int c = 0; c < 4; ++c) acc[r][c] = (f32x4)(0.f);

  const float4 zero4 = make_float4(0.f, 0.f, 0.f, 0.f);
  // stage chunk 0 into buffer 0; prefetch x slice for chunk 1
  float4 xv0 = valid ? *(const float4*)(x + (size_t)gn * FF + w * 4) : zero4;
  stage(xv0, Ah[0]);
  float4 xv_next = valid ? *(const float4*)(x + (size_t)gn * FF + 16 + w * 4) : zero4;
  __syncthreads();

#pragma unroll 2
  for (int kc = 0; kc < NKC; ++kc) {
    // prefetch x slice for chunk kc+2
    float4 xv_pf = zero4;
    if (kc + 2 < NKC && valid)
      xv_pf = *(const float4*)(x + (size_t)gn * FF + (kc + 2) * 16 + w * 4);
    // prefetch B fragments for sk=0 (latency hides under basis VALU below)
    short8 bh_c[4], bh_n[4];
#pragma unroll
    for (int c = 0; c < 4; ++c)
      bh_c[c] = *(const short8*)(Wh + (size_t)(w * 64 + c * 16 + m) * KT +
                                 kc * 192 + quad * 8);
    // stage chunk kc+1's basis into the other buffer
    if (kc + 1 < NKC) stage(xv_next, Ah[(kc + 1) & 1]);
    // MFMA sub-loop over buffer kc&1 with rolling B prefetch
#pragma unroll
    for (int sk = 0; sk < 6; ++sk) {
      if (sk < 5) {
#pragma unroll
        for (int c = 0; c < 4; ++c)
          bh_n[c] = *(const short8*)(Wh + (size_t)(w * 64 + c * 16 + m) * KT +
                                     kc * 192 + (sk + 1) * 32 + quad * 8);
      }
      short8 a[4];
#pragma unroll
      for (int r = 0; r < 4; ++r)
        a[r] = *(const short8*)(&Ah[kc & 1][r * 16 + m][sk * 32 + quad * 8]);
#pragma unroll
      for (int r = 0; r < 4; ++r)
#pragma unroll
        for (int c = 0; c < 4; ++c)
          acc[r][c] = __builtin_amdgcn_mfma_f32_16x16x32_bf16(a[r], bh_c[c], acc[r][c], 0, 0, 0);
#pragma unroll
      for (int c = 0; c < 4; ++c) bh_c[c] = bh_n[c];
    }
    __syncthreads();
    xv_next = xv_pf;
  }
  // epilogue: C/D layout col=lane&15, row=quad*4+reg (verified m89/m91)
#pragma unroll
  for (int r = 0; r < 4; ++r) {
#pragma unroll
    for (int reg = 0; reg < 4; ++reg) {
      int node = block0 + r * 16 + quad * 4 + reg;
      if (node < NN) {
#pragma unroll
        for (int c = 0; c < 4; ++c) {
          int col = w * 64 + c * 16 + m;
          proj[(size_t)node * O2 + col] = acc[r][c][reg];
        }
      }
    }
  }
}

// ---- CSR build ----
__global__ __launch_bounds__(256) void count_kernel(
    const int* __restrict__ ei, int* __restrict__ deg) {
  int e = blockIdx.x * 256 + threadIdx.x;
  if (e < EE) atomicAdd(&deg[ei[EE + e]], 1);
}

// block-level exclusive scan; ex[idx] = excl within block, partial[b] = block sum
__global__ __launch_bounds__(256) void scanA_kernel(
    const int* __restrict__ deg, int* __restrict__ ex, int* __restrict__ partial) {
  __shared__ int sd[256];
  int t = threadIdx.x;
  int idx = blockIdx.x * 256 + t;
  int v = (idx < NN) ? deg[idx] : 0;
  sd[t] = v;
  __syncthreads();
#pragma unroll
  for (int off = 1; off < 256; off <<= 1) {
    int add = (t >= off) ? sd[t - off] : 0;
    __syncthreads();
    sd[t] += add;
    __syncthreads();
  }
  if (idx < NN) ex[idx] = sd[t] - v;
  if (t == 255) partial[blockIdx.x] = sd[255];
}

// single-block exclusive scan of block partials
__global__ __launch_bounds__(256) void scanB_kernel(
    const int* __restrict__ partial, int* __restrict__ poff, int nblk) {
  __shared__ int sd[256];
  int t = threadIdx.x;
  int v = (t < nblk) ? partial[t] : 0;
  sd[t] = v;
  __syncthreads();
#pragma unroll
  for (int off = 1; off < 256; off <<= 1) {
    int add = (t >= off) ? sd[t - off] : 0;
    __syncthreads();
    sd[t] += add;
    __syncthreads();
  }
  if (t < nblk) poff[t] = sd[t] - v;
}

__global__ __launch_bounds__(256) void scanC_kernel(
    const int* __restrict__ ex, const int* __restrict__ poff,
    int* __restrict__ row_ptr) {
  int idx = blockIdx.x * 256 + threadIdx.x;
  if (idx < NN) row_ptr[idx] = ex[idx] + poff[idx >> 8];
  if (idx == 0) row_ptr[NN] = EE;
}

// store SRC id directly; cur[] pre-seeded with row_ptr (no per-edge row_ptr read)
__global__ __launch_bounds__(256) void fill_kernel(
    const int* __restrict__ ei, int* __restrict__ cur, int* __restrict__ scsr) {
  int e = blockIdx.x * 256 + threadIdx.x;
  if (e >= EE) return;
  int s = ei[e];
  int d = ei[EE + e];
  int pos = atomicAdd(&cur[d], 1);
  scsr[pos] = s;
}

// Fused per-dst aggregation: one wave per dst node, single pass over in-edges.
// Online softmax (no max shift: cancels in alpha), no atomics, fused epilogue.
// 2-deep software pipeline: src index prefetched 2 ahead, sp values 1 ahead,
// so each gather's latency is covered by the previous edge's shfl/exp chain.
__global__ __launch_bounds__(256) void aggr_kernel(
    const float* __restrict__ proj, const int* __restrict__ scsr,
    const int* __restrict__ row_ptr, const float* __restrict__ av,
    const float* __restrict__ x, const float* __restrict__ bias,
    const float* __restrict__ pa, float* __restrict__ out) {
  int d = blockIdx.x * 4 + (threadIdx.x >> 6);
  if (d >= NN) return;
  int l = threadIdx.x & 63;
  float dpv1 = proj[(size_t)d * O2 + 128 + l];
  float dpv2 = proj[(size_t)d * O2 + 192 + l];
  float av1 = av[l], av2 = av[64 + l];
  int i0 = row_ptr[d], i1 = row_ptr[d + 1];
  float acc1 = 0.f, acc2 = 0.f, den1 = 0.f, den2 = 0.f;
  if (i0 < i1) {
    int s_cur = scsr[i0];
    int s_nxt = (i0 + 1 < i1) ? scsr[i0 + 1] : s_cur;
    float sp1 = proj[(size_t)s_cur * O2 + l];
    float sp2 = proj[(size_t)s_cur * O2 + 64 + l];
    for (int i = i0; i < i1; ++i) {
      int s_pf = (i + 2 < i1) ? scsr[i + 2] : s_nxt;
      float np1 = proj[(size_t)s_nxt * O2 + l];        // issues immediately
      float np2 = proj[(size_t)s_nxt * O2 + 64 + l];
      float v1 = sp1 + dpv1;
      float v2 = sp2 + dpv2;
      v1 = (v1 >= 0.f) ? v1 : 0.2f * v1;
      v2 = (v2 >= 0.f) ? v2 : 0.2f * v2;
      v1 *= av1;
      v2 *= av2;
#pragma unroll
      for (int off = 1; off < 32; off <<= 1) {  // per-head sums (32-lane groups)
        v1 += __shfl_xor(v1, off, 64);
        v2 += __shfl_xor(v2, off, 64);
      }
      float e1 = __expf(v1), e2 = __expf(v2);
      acc1 += e1 * sp1;
      den1 += e1;
      acc2 += e2 * sp2;
      den2 += e2;
      sp1 = np1;
      sp2 = np2;
      s_nxt = s_pf;
    }
  }
  float a = pa[0];
  float o1 = acc1 / (den1 + 1e-16f) + x[(size_t)d * FF + l] + bias[l];
  float o2 = acc2 / (den2 + 1e-16f) + x[(size_t)d * FF + 64 + l] + bias[64 + l];
  out[(size_t)d * FF + l] = (o1 >= 0.f) ? o1 : a * o1;
  out[(size_t)d * FF + 64 + l] = (o2 >= 0.f) ? o2 : a * o2;
}

extern "C" void kernel_launch(void* const* d_in, const int* in_sizes, int n_in,
                              void* d_out, int out_size, void* d_ws, size_t ws_size,
                              hipStream_t stream) {
  const float* x = (const float*)d_in[0];
  const int* ei = (const int*)d_in[1];
  const float* bws = (const float*)d_in[2];
  const float* sws = (const float*)d_in[3];
  const float* bwd = (const float*)d_in[4];
  const float* swd = (const float*)d_in[5];
  const float* av = (const float*)d_in[6];
  const float* bias = (const float*)d_in[7];
  const float* pa = (const float*)d_in[8];

  // ws layout: Wh | proj | deg | ex | cur | row_ptr | partial | poff | scsr
  ushort* Wh = (ushort*)d_ws;
  float* proj = (float*)(Wh + (size_t)O2 * KT);
  int* deg = (int*)(proj + (size_t)NN * O2);
  int* ex = deg + NN;
  int* cur = ex + NN;
  int* row_ptr = cur + NN;         // NN+1 entries
  int* partial = row_ptr + NN + 1;
  int* poff = partial + 256;
  int* scsr = poff + 256;

  const int NB = (NN + 255) / 256;  // 196 scan blocks

  hipMemsetAsync(deg, 0, (size_t)NN * sizeof(int), stream);

  repack_kernel<<<(O2 * KT + 255) / 256, 256, 0, stream>>>(bws, sws, bwd, swd, Wh);
  proj_mfma_kernel<<<(NN + 63) / 64, 256, 0, stream>>>(x, Wh, proj);
  count_kernel<<<(EE + 255) / 256, 256, 0, stream>>>(ei, deg);
  scanA_kernel<<<NB, 256, 0, stream>>>(deg, ex, partial);
  scanB_kernel<<<1, 256, 0, stream>>>(partial, poff, NB);
  scanC_kernel<<<NB, 256, 0, stream>>>(ex, poff, row_ptr);
  hipMemcpyAsync(cur, row_ptr, (size_t)NN * sizeof(int), hipMemcpyDeviceToDevice, stream);
  fill_kernel<<<(EE + 255) / 256, 256, 0, stream>>>(ei, cur, scsr);
  aggr_kernel<<<(NN + 3) / 4, 256, 0, stream>>>(proj, scsr, row_ptr, av, x, bias, pa,
                                                (float*)d_out);
}

// Round 7
// 363.334 us; speedup vs baseline: 4.0904x; 1.0920x over previous
//
#include <hip/hip_runtime.h>
#include <math.h>

// Problem constants (match reference)
#define NN 50000   // nodes
#define EE 800000  // edges
#define FF 128     // node features
#define CC 11      // spline coeffs per feature (G+K)
#define O2 256     // combined outputs: 128 src-proj + 128 dst-proj
#define KT 1536    // true K: 128 features x 12 slots (11 spline + silu)
#define NKC 8      // K-chunks of 192 (16 features x 12)
#define LDSROW 200 // A-tile row in shorts (192 + 8 pad): 400 B = 100 dw = 4 mod 32 banks (2-way, free)

typedef __attribute__((ext_vector_type(8))) short short8;
typedef __attribute__((ext_vector_type(4))) float f32x4;
typedef unsigned int uint;
typedef unsigned short ushort;

__device__ __forceinline__ ushort bf16_rne(float v) {
  uint u = __float_as_uint(v);
  u = u + 0x7FFFu + ((u >> 16) & 1u);
  return (ushort)(u >> 16);
}

// Repack weights to B^T layout [o2][k] (k contiguous), bf16.
// k = f*12 + ch; ch 0..10 = spline coeff, ch 11 = base (silu) weight
__global__ __launch_bounds__(256) void repack_kernel(
    const float* __restrict__ bws, const float* __restrict__ sws,
    const float* __restrict__ bwd, const float* __restrict__ swd,
    ushort* __restrict__ Wh) {
  int idx = blockIdx.x * 256 + threadIdx.x;
  if (idx >= O2 * KT) return;
  int col = idx / KT;
  int kk = idx - col * KT;
  int f = kk / 12;
  int ch = kk - f * 12;
  const float* bw = (col < 128) ? bws : bwd;
  const float* sw = (col < 128) ? sws : swd;
  int o = col & 127;
  float v = (ch == 11) ? bw[(size_t)o * FF + f] : sw[((size_t)o * FF + f) * CC + ch];
  Wh[idx] = bf16_rne(v);
}

// MFMA KAN projection GEMM. Block = 64 nodes x 256 cols, 4 waves.
// Basis via closed-form cardinal cubic B-spline: at u=4x+7, j=floor(u),
// only bases j-3..j are nonzero (weights (1-t)^3/6, (4-6t^2+3t^3)/6,
// (1+3t+3t^2-3t^3)/6, t^3/6) — matches the reference Cox-de-Boor on its
// uniform extended grid. Double-buffered A-tile, one barrier per chunk.
// Output: bf16-packed projB[node][p]: p=q*16+m holds cols (q*32+m, q*32+16+m).
__global__ __launch_bounds__(256) void proj_mfma_kernel(
    const float* __restrict__ x, const ushort* __restrict__ Wh,
    uint* __restrict__ projB) {
  __shared__ ushort Ah[2][64][LDSROW];  // 51.2 KB
  const int t = threadIdx.x;
  const int lane = t & 63;
  const int w = t >> 6;      // wave 0..3
  const int m = lane & 15;
  const int quad = lane >> 4;
  const int block0 = blockIdx.x * 64;
  const int gn = block0 + lane;  // staging: node = lane, feature group = wave
  const bool valid = (gn < NN);

  auto stage = [&](float4 xvv, ushort(*buf)[LDSROW]) {
    float xa[4] = {xvv.x, xvv.y, xvv.z, xvv.w};
    // zero this thread's 48-short (96 B) region, then scatter nonzeros
    uint4* dz = (uint4*)&buf[lane][w * 48];
#pragma unroll
    for (int i = 0; i < 6; ++i) dz[i] = make_uint4(0u, 0u, 0u, 0u);
#pragma unroll
    for (int jf = 0; jf < 4; ++jf) {
      float xv = xa[jf];
      ushort* row = &buf[lane][w * 48 + jf * 12];
      row[11] = bf16_rne(xv / (1.f + __expf(-xv)));  // silu slot
      float u = fmaf(xv, 4.f, 7.f);
      float fj = floorf(u);
      int j = (int)fj;
      if (j >= 0 && j <= 13) {
        float tt = u - fj;
        float t2 = tt * tt, t3 = t2 * tt;
        float w0 = (1.f / 6.f) * (1.f - 3.f * tt + 3.f * t2 - t3);
        float w1 = (1.f / 6.f) * (4.f - 6.f * t2 + 3.f * t3);
        float w2 = (1.f / 6.f) * (1.f + 3.f * tt + 3.f * t2 - 3.f * t3);
        float w3 = (1.f / 6.f) * t3;
        float wv[4] = {w0, w1, w2, w3};
        int i0 = j - 3;
#pragma unroll
        for (int c = 0; c < 4; ++c) {
          int idx = i0 + c;
          if (idx >= 0 && idx <= 10) row[idx] = bf16_rne(wv[c]);
        }
      }
    }
  };

  f32x4 acc[4][4];
#pragma unroll
  for (int r = 0; r < 4; ++r)
#pragma unroll
    for (int c = 0; c < 4; ++c) acc[r][c] = (f32x4)(0.f);

  const float4 zero4 = make_float4(0.f, 0.f, 0.f, 0.f);
  float4 xv0 = valid ? *(const float4*)(x + (size_t)gn * FF + w * 4) : zero4;
  stage(xv0, Ah[0]);
  float4 xv_next = valid ? *(const float4*)(x + (size_t)gn * FF + 16 + w * 4) : zero4;
  __syncthreads();

#pragma unroll 2
  for (int kc = 0; kc < NKC; ++kc) {
    float4 xv_pf = zero4;
    if (kc + 2 < NKC && valid)
      xv_pf = *(const float4*)(x + (size_t)gn * FF + (kc + 2) * 16 + w * 4);
    short8 bh_c[4], bh_n[4];
#pragma unroll
    for (int c = 0; c < 4; ++c)
      bh_c[c] = *(const short8*)(Wh + (size_t)(w * 64 + c * 16 + m) * KT +
                                 kc * 192 + quad * 8);
    if (kc + 1 < NKC) stage(xv_next, Ah[(kc + 1) & 1]);
#pragma unroll
    for (int sk = 0; sk < 6; ++sk) {
      if (sk < 5) {
#pragma unroll
        for (int c = 0; c < 4; ++c)
          bh_n[c] = *(const short8*)(Wh + (size_t)(w * 64 + c * 16 + m) * KT +
                                     kc * 192 + (sk + 1) * 32 + quad * 8);
      }
      short8 a[4];
#pragma unroll
      for (int r = 0; r < 4; ++r)
        a[r] = *(const short8*)(&Ah[kc & 1][r * 16 + m][sk * 32 + quad * 8]);
#pragma unroll
      for (int r = 0; r < 4; ++r)
#pragma unroll
        for (int c = 0; c < 4; ++c)
          acc[r][c] = __builtin_amdgcn_mfma_f32_16x16x32_bf16(a[r], bh_c[c], acc[r][c], 0, 0, 0);
#pragma unroll
      for (int c = 0; c < 4; ++c) bh_c[c] = bh_n[c];
    }
    __syncthreads();
    xv_next = xv_pf;
  }
  // epilogue: C/D layout col=lane&15, row=quad*4+reg (verified m89/m91).
  // acc[r][c] holds col = w*64 + c*16 + m -> pack c-pairs (0,1) and (2,3):
  // uint index p = q*16 + m with q = 2w + (c>>1); covers cols (q*32+m, +16).
#pragma unroll
  for (int r = 0; r < 4; ++r) {
#pragma unroll
    for (int reg = 0; reg < 4; ++reg) {
      int node = block0 + r * 16 + quad * 4 + reg;
      if (node < NN) {
#pragma unroll
        for (int cp = 0; cp < 2; ++cp) {
          int q = 2 * w + cp;
          uint val = (uint)bf16_rne(acc[r][2 * cp][reg]) |
                     ((uint)bf16_rne(acc[r][2 * cp + 1][reg]) << 16);
          projB[(size_t)node * 128 + q * 16 + m] = val;
        }
      }
    }
  }
}

// ---- CSR build ----
__global__ __launch_bounds__(256) void count_kernel(
    const int* __restrict__ ei, int* __restrict__ deg) {
  int e = blockIdx.x * 256 + threadIdx.x;
  if (e < EE) atomicAdd(&deg[ei[EE + e]], 1);
}

__global__ __launch_bounds__(256) void scanA_kernel(
    const int* __restrict__ deg, int* __restrict__ ex, int* __restrict__ partial) {
  __shared__ int sd[256];
  int t = threadIdx.x;
  int idx = blockIdx.x * 256 + t;
  int v = (idx < NN) ? deg[idx] : 0;
  sd[t] = v;
  __syncthreads();
#pragma unroll
  for (int off = 1; off < 256; off <<= 1) {
    int add = (t >= off) ? sd[t - off] : 0;
    __syncthreads();
    sd[t] += add;
    __syncthreads();
  }
  if (idx < NN) ex[idx] = sd[t] - v;
  if (t == 255) partial[blockIdx.x] = sd[255];
}

__global__ __launch_bounds__(256) void scanB_kernel(
    const int* __restrict__ partial, int* __restrict__ poff, int nblk) {
  __shared__ int sd[256];
  int t = threadIdx.x;
  int v = (t < nblk) ? partial[t] : 0;
  sd[t] = v;
  __syncthreads();
#pragma unroll
  for (int off = 1; off < 256; off <<= 1) {
    int add = (t >= off) ? sd[t - off] : 0;
    __syncthreads();
    sd[t] += add;
    __syncthreads();
  }
  if (t < nblk) poff[t] = sd[t] - v;
}

__global__ __launch_bounds__(256) void scanC_kernel(
    const int* __restrict__ ex, const int* __restrict__ poff,
    int* __restrict__ row_ptr) {
  int idx = blockIdx.x * 256 + threadIdx.x;
  if (idx < NN) row_ptr[idx] = ex[idx] + poff[idx >> 8];
  if (idx == 0) row_ptr[NN] = EE;
}

// store SRC id directly; cur[] pre-seeded with row_ptr
__global__ __launch_bounds__(256) void fill_kernel(
    const int* __restrict__ ei, int* __restrict__ cur, int* __restrict__ scsr) {
  int e = blockIdx.x * 256 + threadIdx.x;
  if (e >= EE) return;
  int s = ei[e];
  int d = ei[EE + e];
  int pos = atomicAdd(&cur[d], 1);
  scsr[pos] = s;
}

// Fused per-dst aggregation: one wave per dst, single pass over in-edges.
// bf16-packed gather: lane l = q*16+m owns head q, cols (q*32+m, q*32+16+m);
// one 4 B load per lane per edge; 4-shfl per-head score reduce.
__global__ __launch_bounds__(256) void aggr_kernel(
    const uint* __restrict__ projB, const int* __restrict__ scsr,
    const int* __restrict__ row_ptr, const float* __restrict__ av,
    const float* __restrict__ x, const float* __restrict__ bias,
    const float* __restrict__ pa, float* __restrict__ out) {
  int d = blockIdx.x * 4 + (threadIdx.x >> 6);
  if (d >= NN) return;
  int l = threadIdx.x & 63;
  int q = l >> 4, m = l & 15;
  int col0 = q * 32 + m, col1 = col0 + 16;
  uint dpu = projB[(size_t)d * 128 + 64 + l];
  float dp0 = __uint_as_float(dpu << 16);
  float dp1 = __uint_as_float(dpu & 0xffff0000u);
  float a0 = av[col0], a1 = av[col1];
  int i0 = row_ptr[d], i1 = row_ptr[d + 1];
  float acc0 = 0.f, acc1 = 0.f, den = 0.f;
  if (i0 < i1) {
    int s_cur = scsr[i0];
    int s_nxt = (i0 + 1 < i1) ? scsr[i0 + 1] : s_cur;
    uint spu = projB[(size_t)s_cur * 128 + l];
    for (int i = i0; i < i1; ++i) {
      int s_pf = (i + 2 < i1) ? scsr[i + 2] : s_nxt;
      uint npu = projB[(size_t)s_nxt * 128 + l];  // issues immediately
      float sp0 = __uint_as_float(spu << 16);
      float sp1 = __uint_as_float(spu & 0xffff0000u);
      float v0 = sp0 + dp0;
      float v1 = sp1 + dp1;
      v0 = (v0 >= 0.f) ? v0 : 0.2f * v0;
      v1 = (v1 >= 0.f) ? v1 : 0.2f * v1;
      float vp = v0 * a0 + v1 * a1;
#pragma unroll
      for (int off = 1; off < 16; off <<= 1)  // reduce within 16-lane head group
        vp += __shfl_xor(vp, off, 64);
      float e = __expf(vp);
      acc0 += e * sp0;
      acc1 += e * sp1;
      den += e;
      spu = npu;
      s_nxt = s_pf;
    }
  }
  float a = pa[0];
  float r = 1.f / (den + 1e-16f);
  float o0 = acc0 * r + x[(size_t)d * FF + col0] + bias[col0];
  float o1 = acc1 * r + x[(size_t)d * FF + col1] + bias[col1];
  out[(size_t)d * FF + col0] = (o0 >= 0.f) ? o0 : a * o0;
  out[(size_t)d * FF + col1] = (o1 >= 0.f) ? o1 : a * o1;
}

extern "C" void kernel_launch(void* const* d_in, const int* in_sizes, int n_in,
                              void* d_out, int out_size, void* d_ws, size_t ws_size,
                              hipStream_t stream) {
  const float* x = (const float*)d_in[0];
  const int* ei = (const int*)d_in[1];
  const float* bws = (const float*)d_in[2];
  const float* sws = (const float*)d_in[3];
  const float* bwd = (const float*)d_in[4];
  const float* swd = (const float*)d_in[5];
  const float* av = (const float*)d_in[6];
  const float* bias = (const float*)d_in[7];
  const float* pa = (const float*)d_in[8];

  // ws layout: Wh | projB | deg | ex | cur | row_ptr | partial | poff | scsr
  ushort* Wh = (ushort*)d_ws;
  uint* projB = (uint*)(Wh + (size_t)O2 * KT);
  int* deg = (int*)(projB + (size_t)NN * 128);
  int* ex = deg + NN;
  int* cur = ex + NN;
  int* row_ptr = cur + NN;         // NN+1 entries
  int* partial = row_ptr + NN + 1;
  int* poff = partial + 256;
  int* scsr = poff + 256;

  const int NB = (NN + 255) / 256;  // 196 scan blocks

  hipMemsetAsync(deg, 0, (size_t)NN * sizeof(int), stream);

  repack_kernel<<<(O2 * KT + 255) / 256, 256, 0, stream>>>(bws, sws, bwd, swd, Wh);
  proj_mfma_kernel<<<(NN + 63) / 64, 256, 0, stream>>>(x, Wh, projB);
  count_kernel<<<(EE + 255) / 256, 256, 0, stream>>>(ei, deg);
  scanA_kernel<<<NB, 256, 0, stream>>>(deg, ex, partial);
  scanB_kernel<<<1, 256, 0, stream>>>(partial, poff, NB);
  scanC_kernel<<<NB, 256, 0, stream>>>(ex, poff, row_ptr);
  hipMemcpyAsync(cur, row_ptr, (size_t)NN * sizeof(int), hipMemcpyDeviceToDevice, stream);
  fill_kernel<<<(EE + 255) / 256, 256, 0, stream>>>(ei, cur, scsr);
  aggr_kernel<<<(NN + 3) / 4, 256, 0, stream>>>(projB, scsr, row_ptr, av, x, bias, pa,
                                                (float*)d_out);
}

// Round 8
// 329.341 us; speedup vs baseline: 4.5126x; 1.1032x over previous
//
#include <hip/hip_runtime.h>
#include <math.h>

// Problem constants (match reference)
#define NN 50000   // nodes
#define EE 800000  // edges
#define FF 128     // node features
#define CC 11      // spline coeffs per feature (G+K)
#define O2 256     // combined outputs: 128 src-proj + 128 dst-proj
#define KT 1536    // true K: 128 features x 12 slots (11 spline + silu)
#define NCH 16     // K-chunks of 96 (8 features x 12)
#define AROW 104   // A-tile row in shorts (96 + 8 pad): 208 B = 52 dw = 20 mod 32 banks -> 8-phase min

typedef __attribute__((ext_vector_type(8))) short short8;
typedef __attribute__((ext_vector_type(4))) float f32x4;
typedef unsigned int uint;
typedef unsigned short ushort;

__device__ __forceinline__ ushort bf16_rne(float v) {
  uint u = __float_as_uint(v);
  u = u + 0x7FFFu + ((u >> 16) & 1u);
  return (ushort)(u >> 16);
}
__device__ __forceinline__ float bf_lo(uint u) { return __uint_as_float(u << 16); }
__device__ __forceinline__ float bf_hi(uint u) { return __uint_as_float(u & 0xffff0000u); }

// Fused: repack weights to B^T bf16 [o2][k] (idx < O2*KT) + degree count (idx < EE)
__global__ __launch_bounds__(256) void repack_count_kernel(
    const float* __restrict__ bws, const float* __restrict__ sws,
    const float* __restrict__ bwd, const float* __restrict__ swd,
    ushort* __restrict__ Wh, const int* __restrict__ ei, int* __restrict__ deg) {
  int idx = blockIdx.x * 256 + threadIdx.x;
  if (idx < O2 * KT) {
    int col = idx / KT;
    int kk = idx - col * KT;
    int f = kk / 12;
    int ch = kk - f * 12;
    const float* bw = (col < 128) ? bws : bwd;
    const float* sw = (col < 128) ? sws : swd;
    int o = col & 127;
    float v = (ch == 11) ? bw[(size_t)o * FF + f] : sw[((size_t)o * FF + f) * CC + ch];
    Wh[idx] = bf16_rne(v);
  }
  if (idx < EE) atomicAdd(&deg[ei[EE + idx]], 1);
}

// MFMA KAN projection GEMM. Block = 64 nodes x 256 cols, 4 waves.
// Closed-form cardinal cubic basis (4 nonzero weights at u=4x+7).
// K chunked by 96 (8 features), double-buffered A-tile (13.3 KB each),
// one barrier per chunk. Output bf16-packed projB[node][p]:
// p=q*16+m holds cols (q*32+m, q*32+16+m).
__global__ __launch_bounds__(256) void proj_mfma_kernel(
    const float* __restrict__ x, const ushort* __restrict__ Wh,
    uint* __restrict__ projB) {
  __shared__ ushort Ah[2][64][AROW];  // 26.6 KB total
  const int t = threadIdx.x;
  const int lane = t & 63;
  const int w = t >> 6;      // wave 0..3
  const int m = lane & 15;
  const int quad = lane >> 4;
  const int block0 = blockIdx.x * 64;
  const int node = t & 63;          // staging: node = t&63, feature pair = t>>6
  const int fi = t >> 6;            // 0..3 -> features fi*2, fi*2+1 of chunk
  const int sgn = block0 + node;
  const bool svalid = (sgn < NN);

  // stage 2 features (24 slots) for one node into buf
  auto stage = [&](float2 xv, ushort(*buf)[AROW]) {
    uint4* dz = (uint4*)&buf[node][fi * 24];
    dz[0] = make_uint4(0u, 0u, 0u, 0u);
    dz[1] = make_uint4(0u, 0u, 0u, 0u);
    dz[2] = make_uint4(0u, 0u, 0u, 0u);
    float xa[2] = {xv.x, xv.y};
#pragma unroll
    for (int u2 = 0; u2 < 2; ++u2) {
      float xvv = xa[u2];
      ushort* row = &buf[node][(fi * 2 + u2) * 12];
      row[11] = bf16_rne(xvv / (1.f + __expf(-xvv)));  // silu slot
      float u = fmaf(xvv, 4.f, 7.f);
      float fj = floorf(u);
      int j = (int)fj;
      if (j >= 0 && j <= 13) {
        float tt = u - fj;
        float t2 = tt * tt, t3 = t2 * tt;
        float w0 = (1.f / 6.f) * (1.f - 3.f * tt + 3.f * t2 - t3);
        float w1 = (1.f / 6.f) * (4.f - 6.f * t2 + 3.f * t3);
        float w2 = (1.f / 6.f) * (1.f + 3.f * tt + 3.f * t2 - 3.f * t3);
        float w3 = (1.f / 6.f) * t3;
        float wv[4] = {w0, w1, w2, w3};
        int i0 = j - 3;
#pragma unroll
        for (int c = 0; c < 4; ++c) {
          int idx = i0 + c;
          if (idx >= 0 && idx <= 10) row[idx] = bf16_rne(wv[c]);
        }
      }
    }
  };

  f32x4 acc[4][4];
#pragma unroll
  for (int r = 0; r < 4; ++r)
#pragma unroll
    for (int c = 0; c < 4; ++c) acc[r][c] = (f32x4)(0.f);

  const float2 zero2 = make_float2(0.f, 0.f);
  float2 xv0 = svalid ? *(const float2*)(x + (size_t)sgn * FF + fi * 2) : zero2;
  stage(xv0, Ah[0]);
  float2 xv_next = svalid ? *(const float2*)(x + (size_t)sgn * FF + 8 + fi * 2) : zero2;
  __syncthreads();

  for (int kc = 0; kc < NCH; ++kc) {
    float2 xv_pf = zero2;
    if (kc + 2 < NCH && svalid)
      xv_pf = *(const float2*)(x + (size_t)sgn * FF + (kc + 2) * 8 + fi * 2);
    // prefetch B for sk=0 (latency hides under next-chunk staging VALU)
    short8 bh_c[4], bh_n[4];
#pragma unroll
    for (int c = 0; c < 4; ++c)
      bh_c[c] = *(const short8*)(Wh + (size_t)(w * 64 + c * 16 + m) * KT +
                                 kc * 96 + quad * 8);
    if (kc + 1 < NCH) stage(xv_next, Ah[(kc + 1) & 1]);
#pragma unroll
    for (int sk = 0; sk < 3; ++sk) {
      if (sk < 2) {
#pragma unroll
        for (int c = 0; c < 4; ++c)
          bh_n[c] = *(const short8*)(Wh + (size_t)(w * 64 + c * 16 + m) * KT +
                                     kc * 96 + (sk + 1) * 32 + quad * 8);
      }
      short8 a[4];
#pragma unroll
      for (int r = 0; r < 4; ++r)
        a[r] = *(const short8*)(&Ah[kc & 1][r * 16 + m][sk * 32 + quad * 8]);
#pragma unroll
      for (int r = 0; r < 4; ++r)
#pragma unroll
        for (int c = 0; c < 4; ++c)
          acc[r][c] = __builtin_amdgcn_mfma_f32_16x16x32_bf16(a[r], bh_c[c], acc[r][c], 0, 0, 0);
#pragma unroll
      for (int c = 0; c < 4; ++c) bh_c[c] = bh_n[c];
    }
    __syncthreads();
    xv_next = xv_pf;
  }
  // epilogue: C/D layout col=lane&15, row=quad*4+reg (verified m89/m91).
  // pack c-pairs: p = q*16 + m, q = 2w + cp -> cols (q*32+m, q*32+16+m)
#pragma unroll
  for (int r = 0; r < 4; ++r) {
#pragma unroll
    for (int reg = 0; reg < 4; ++reg) {
      int nd = block0 + r * 16 + quad * 4 + reg;
      if (nd < NN) {
#pragma unroll
        for (int cp = 0; cp < 2; ++cp) {
          int q = 2 * w + cp;
          uint val = (uint)bf16_rne(acc[r][2 * cp][reg]) |
                     ((uint)bf16_rne(acc[r][2 * cp + 1][reg]) << 16);
          projB[(size_t)nd * 128 + q * 16 + m] = val;
        }
      }
    }
  }
}

// ---- CSR build ----
__global__ __launch_bounds__(256) void scanA_kernel(
    const int* __restrict__ deg, int* __restrict__ ex, int* __restrict__ partial) {
  __shared__ int sd[256];
  int t = threadIdx.x;
  int idx = blockIdx.x * 256 + t;
  int v = (idx < NN) ? deg[idx] : 0;
  sd[t] = v;
  __syncthreads();
#pragma unroll
  for (int off = 1; off < 256; off <<= 1) {
    int add = (t >= off) ? sd[t - off] : 0;
    __syncthreads();
    sd[t] += add;
    __syncthreads();
  }
  if (idx < NN) ex[idx] = sd[t] - v;
  if (t == 255) partial[blockIdx.x] = sd[255];
}

__global__ __launch_bounds__(256) void scanB_kernel(
    const int* __restrict__ partial, int* __restrict__ poff, int nblk) {
  __shared__ int sd[256];
  int t = threadIdx.x;
  int v = (t < nblk) ? partial[t] : 0;
  sd[t] = v;
  __syncthreads();
#pragma unroll
  for (int off = 1; off < 256; off <<= 1) {
    int add = (t >= off) ? sd[t - off] : 0;
    __syncthreads();
    sd[t] += add;
    __syncthreads();
  }
  if (t < nblk) poff[t] = sd[t] - v;
}

// row_ptr + seed cur (removes the d2d memcpy)
__global__ __launch_bounds__(256) void scanC_kernel(
    const int* __restrict__ ex, const int* __restrict__ poff,
    int* __restrict__ row_ptr, int* __restrict__ cur) {
  int idx = blockIdx.x * 256 + threadIdx.x;
  if (idx < NN) {
    int v = ex[idx] + poff[idx >> 8];
    row_ptr[idx] = v;
    cur[idx] = v;
  }
  if (idx == 0) row_ptr[NN] = EE;
}

__global__ __launch_bounds__(256) void fill_kernel(
    const int* __restrict__ ei, int* __restrict__ cur, int* __restrict__ scsr) {
  int e = blockIdx.x * 256 + threadIdx.x;
  if (e >= EE) return;
  int s = ei[e];
  int d = ei[EE + e];
  int pos = atomicAdd(&cur[d], 1);
  scsr[pos] = s;
}

// Per-dst aggregation: one wave per dst, 4 edges in flight (16-lane groups).
// Lane l: group g=l>>4 (edge i0+g, stride 4), m=l&15 -> uint4 = p 4m..4m+3,
// covering head m>>2 only -> score reduce is 2 shfls in the 4-lane subgroup.
// Cross-group combine once at the end; fused residual+bias+PReLU epilogue.
__global__ __launch_bounds__(256) void aggr_kernel(
    const uint* __restrict__ projB, const int* __restrict__ scsr,
    const int* __restrict__ row_ptr, const float* __restrict__ av,
    const float* __restrict__ x, const float* __restrict__ bias,
    const float* __restrict__ pa, float* __restrict__ out) {
  int d = blockIdx.x * 4 + (threadIdx.x >> 6);
  if (d >= NN) return;
  int l = threadIdx.x & 63;
  int g = l >> 4, m = l & 15;
  const uint4* pb4 = (const uint4*)projB;
  uint4 dpu = pb4[(size_t)d * 32 + 16 + m];
  uint du[4] = {dpu.x, dpu.y, dpu.z, dpu.w};
  float dplo[4], dphi[4], avlo[4], avhi[4];
  int cl[4];
#pragma unroll
  for (int j = 0; j < 4; ++j) {
    dplo[j] = bf_lo(du[j]);
    dphi[j] = bf_hi(du[j]);
    int p = 4 * m + j;
    cl[j] = ((p >> 4) << 5) + (p & 15);
    avlo[j] = av[cl[j]];
    avhi[j] = av[cl[j] + 16];
  }
  int i0 = row_ptr[d], i1 = row_ptr[d + 1];
  float acl[4] = {0.f, 0.f, 0.f, 0.f}, ach[4] = {0.f, 0.f, 0.f, 0.f};
  float den = 0.f;
  int i = i0 + g;
  if (i < i1) {
    int s_cur = scsr[i];
    int s_nxt = (i + 4 < i1) ? scsr[i + 4] : s_cur;
    uint4 U = pb4[(size_t)s_cur * 32 + m];
    for (; i < i1; i += 4) {
      int s_pf = (i + 8 < i1) ? scsr[i + 8] : s_nxt;
      uint4 Un = pb4[(size_t)s_nxt * 32 + m];  // issues immediately
      uint uu[4] = {U.x, U.y, U.z, U.w};
      float slo[4], shi[4];
      float vp = 0.f;
#pragma unroll
      for (int j = 0; j < 4; ++j) {
        slo[j] = bf_lo(uu[j]);
        shi[j] = bf_hi(uu[j]);
        float v0 = slo[j] + dplo[j];
        float v1 = shi[j] + dphi[j];
        v0 = (v0 >= 0.f) ? v0 : 0.2f * v0;
        v1 = (v1 >= 0.f) ? v1 : 0.2f * v1;
        vp = fmaf(v0, avlo[j], vp);
        vp = fmaf(v1, avhi[j], vp);
      }
      vp += __shfl_xor(vp, 1, 64);  // head-local reduce (4-lane subgroup)
      vp += __shfl_xor(vp, 2, 64);
      float e = __expf(vp);
#pragma unroll
      for (int j = 0; j < 4; ++j) {
        acl[j] = fmaf(e, slo[j], acl[j]);
        ach[j] = fmaf(e, shi[j], ach[j]);
      }
      den += e;
      U = Un;
      s_nxt = s_pf;
    }
  }
  // combine the 4 edge-groups (heads preserved: lanes with same m align)
#pragma unroll
  for (int off = 16; off < 64; off <<= 1) {
    den += __shfl_xor(den, off, 64);
#pragma unroll
    for (int j = 0; j < 4; ++j) {
      acl[j] += __shfl_xor(acl[j], off, 64);
      ach[j] += __shfl_xor(ach[j], off, 64);
    }
  }
  if (g == 0) {
    float a = pa[0];
    float r = 1.f / (den + 1e-16f);
#pragma unroll
    for (int j = 0; j < 4; ++j) {
      float o0 = acl[j] * r + x[(size_t)d * FF + cl[j]] + bias[cl[j]];
      float o1 = ach[j] * r + x[(size_t)d * FF + cl[j] + 16] + bias[cl[j] + 16];
      out[(size_t)d * FF + cl[j]] = (o0 >= 0.f) ? o0 : a * o0;
      out[(size_t)d * FF + cl[j] + 16] = (o1 >= 0.f) ? o1 : a * o1;
    }
  }
}

extern "C" void kernel_launch(void* const* d_in, const int* in_sizes, int n_in,
                              void* d_out, int out_size, void* d_ws, size_t ws_size,
                              hipStream_t stream) {
  const float* x = (const float*)d_in[0];
  const int* ei = (const int*)d_in[1];
  const float* bws = (const float*)d_in[2];
  const float* sws = (const float*)d_in[3];
  const float* bwd = (const float*)d_in[4];
  const float* swd = (const float*)d_in[5];
  const float* av = (const float*)d_in[6];
  const float* bias = (const float*)d_in[7];
  const float* pa = (const float*)d_in[8];

  // ws layout: Wh | projB | deg | ex | cur | row_ptr | partial | poff | scsr
  ushort* Wh = (ushort*)d_ws;
  uint* projB = (uint*)(Wh + (size_t)O2 * KT);
  int* deg = (int*)(projB + (size_t)NN * 128);
  int* ex = deg + NN;
  int* cur = ex + NN;
  int* row_ptr = cur + NN;         // NN+1 entries
  int* partial = row_ptr + NN + 1;
  int* poff = partial + 256;
  int* scsr = poff + 256;

  const int NB = (NN + 255) / 256;  // 196 scan blocks

  hipMemsetAsync(deg, 0, (size_t)NN * sizeof(int), stream);

  repack_count_kernel<<<(EE + 255) / 256, 256, 0, stream>>>(bws, sws, bwd, swd, Wh, ei, deg);
  proj_mfma_kernel<<<(NN + 63) / 64, 256, 0, stream>>>(x, Wh, projB);
  scanA_kernel<<<NB, 256, 0, stream>>>(deg, ex, partial);
  scanB_kernel<<<1, 256, 0, stream>>>(partial, poff, NB);
  scanC_kernel<<<NB, 256, 0, stream>>>(ex, poff, row_ptr, cur);
  fill_kernel<<<(EE + 255) / 256, 256, 0, stream>>>(ei, cur, scsr);
  aggr_kernel<<<(NN + 3) / 4, 256, 0, stream>>>(projB, scsr, row_ptr, av, x, bias, pa,
                                                (float*)d_out);
}

// Round 9
// 304.130 us; speedup vs baseline: 4.8867x; 1.0829x over previous
//
#include <hip/hip_runtime.h>
#include <math.h>

// Problem constants (match reference)
#define NN 50000   // nodes
#define EE 800000  // edges
#define FF 128     // node features
#define CC 11      // spline coeffs per feature (G+K)
#define O2 256     // combined outputs: 128 src-proj + 128 dst-proj
#define KT 1536    // true K: 128 features x 12 slots (11 spline + silu)
#define NKC 8      // K-chunks of 192 (16 features x 12)
#define AROW 200   // A-tile row in shorts (192 + 8 pad): 400 B = 100 dw = 4 mod 32 banks (2-way, free)
#define NPB 782    // proj blocks: ceil(NN/64)
#define NCB 782    // count blocks: ceil(EE/(256*4))

typedef __attribute__((ext_vector_type(8))) short short8;
typedef __attribute__((ext_vector_type(4))) float f32x4;
typedef unsigned int uint;
typedef unsigned short ushort;

__device__ __forceinline__ ushort bf16_rne(float v) {
  uint u = __float_as_uint(v);
  u = u + 0x7FFFu + ((u >> 16) & 1u);
  return (ushort)(u >> 16);
}
__device__ __forceinline__ float bf_lo(uint u) { return __uint_as_float(u << 16); }
__device__ __forceinline__ float bf_hi(uint u) { return __uint_as_float(u & 0xffff0000u); }

// Repack weights to B^T bf16 [o2][k] + zero deg (fused, removes memset dispatch)
__global__ __launch_bounds__(256) void repack_zero_kernel(
    const float* __restrict__ bws, const float* __restrict__ sws,
    const float* __restrict__ bwd, const float* __restrict__ swd,
    ushort* __restrict__ Wh, int* __restrict__ deg) {
  int idx = blockIdx.x * 256 + threadIdx.x;
  if (idx < NN) deg[idx] = 0;
  if (idx >= O2 * KT) return;
  int col = idx / KT;
  int kk = idx - col * KT;
  int f = kk / 12;
  int ch = kk - f * 12;
  const float* bw = (col < 128) ? bws : bwd;
  const float* sw = (col < 128) ? sws : swd;
  int o = col & 127;
  float v = (ch == 11) ? bw[(size_t)o * FF + f] : sw[((size_t)o * FF + f) * CC + ch];
  Wh[idx] = bf16_rne(v);
}

// Fused dispatch: blocks [0,NPB) = MFMA projection; blocks [NPB,NPB+NCB) =
// degree count (4 edges/thread, int4). Count blocks backfill the CU slots
// proj's latency stalls leave idle — count leaves the critical path.
//
// Projection: block = 64 nodes x 256 cols, 4 waves. Closed-form cardinal
// cubic basis (4 nonzero weights at u=4x+7). K chunked by 192 (16 features),
// double-buffered A-tile, one barrier per chunk. Output bf16-packed
// projB[node][p]: p=q*16+m holds cols (q*32+m, q*32+16+m).
__global__ __launch_bounds__(256) void proj_count_kernel(
    const float* __restrict__ x, const ushort* __restrict__ Wh,
    uint* __restrict__ projB, const int* __restrict__ ei, int* __restrict__ deg) {
  __shared__ ushort Ah[2][64][AROW];  // 51.2 KB
  if (blockIdx.x >= NPB) {  // ---- count part ----
    int base = ((blockIdx.x - NPB) * 256 + threadIdx.x) * 4;
    if (base + 3 < EE) {
      int4 dd = *(const int4*)(ei + EE + base);
      atomicAdd(&deg[dd.x], 1);
      atomicAdd(&deg[dd.y], 1);
      atomicAdd(&deg[dd.z], 1);
      atomicAdd(&deg[dd.w], 1);
    } else {
      for (int j = 0; j < 4 && base + j < EE; ++j) atomicAdd(&deg[ei[EE + base + j]], 1);
    }
    return;
  }
  const int t = threadIdx.x;
  const int lane = t & 63;
  const int w = t >> 6;      // wave 0..3
  const int m = lane & 15;
  const int quad = lane >> 4;
  const int block0 = blockIdx.x * 64;
  const int gn = block0 + lane;  // staging: node = lane, feature group = wave
  const bool valid = (gn < NN);

  auto stage = [&](float4 xvv, ushort(*buf)[AROW]) {
    float xa[4] = {xvv.x, xvv.y, xvv.z, xvv.w};
    uint4* dz = (uint4*)&buf[lane][w * 48];
#pragma unroll
    for (int i = 0; i < 6; ++i) dz[i] = make_uint4(0u, 0u, 0u, 0u);
#pragma unroll
    for (int jf = 0; jf < 4; ++jf) {
      float xv = xa[jf];
      ushort* row = &buf[lane][w * 48 + jf * 12];
      row[11] = bf16_rne(xv / (1.f + __expf(-xv)));  // silu slot
      float u = fmaf(xv, 4.f, 7.f);
      float fj = floorf(u);
      int j = (int)fj;
      if (j >= 0 && j <= 13) {
        float tt = u - fj;
        float t2 = tt * tt, t3 = t2 * tt;
        float w0 = (1.f / 6.f) * (1.f - 3.f * tt + 3.f * t2 - t3);
        float w1 = (1.f / 6.f) * (4.f - 6.f * t2 + 3.f * t3);
        float w2 = (1.f / 6.f) * (1.f + 3.f * tt + 3.f * t2 - 3.f * t3);
        float w3 = (1.f / 6.f) * t3;
        float wv[4] = {w0, w1, w2, w3};
        int i0 = j - 3;
#pragma unroll
        for (int c = 0; c < 4; ++c) {
          int idx = i0 + c;
          if (idx >= 0 && idx <= 10) row[idx] = bf16_rne(wv[c]);
        }
      }
    }
  };

  f32x4 acc[4][4];
#pragma unroll
  for (int r = 0; r < 4; ++r)
#pragma unroll
    for (int c = 0; c < 4; ++c) acc[r][c] = (f32x4)(0.f);

  const float4 zero4 = make_float4(0.f, 0.f, 0.f, 0.f);
  float4 xv0 = valid ? *(const float4*)(x + (size_t)gn * FF + w * 4) : zero4;
  stage(xv0, Ah[0]);
  float4 xv_next = valid ? *(const float4*)(x + (size_t)gn * FF + 16 + w * 4) : zero4;
  __syncthreads();

#pragma unroll 2
  for (int kc = 0; kc < NKC; ++kc) {
    float4 xv_pf = zero4;
    if (kc + 2 < NKC && valid)
      xv_pf = *(const float4*)(x + (size_t)gn * FF + (kc + 2) * 16 + w * 4);
    short8 bh_c[4], bh_n[4];
#pragma unroll
    for (int c = 0; c < 4; ++c)
      bh_c[c] = *(const short8*)(Wh + (size_t)(w * 64 + c * 16 + m) * KT +
                                 kc * 192 + quad * 8);
    if (kc + 1 < NKC) stage(xv_next, Ah[(kc + 1) & 1]);
#pragma unroll
    for (int sk = 0; sk < 6; ++sk) {
      if (sk < 5) {
#pragma unroll
        for (int c = 0; c < 4; ++c)
          bh_n[c] = *(const short8*)(Wh + (size_t)(w * 64 + c * 16 + m) * KT +
                                     kc * 192 + (sk + 1) * 32 + quad * 8);
      }
      short8 a[4];
#pragma unroll
      for (int r = 0; r < 4; ++r)
        a[r] = *(const short8*)(&Ah[kc & 1][r * 16 + m][sk * 32 + quad * 8]);
#pragma unroll
      for (int r = 0; r < 4; ++r)
#pragma unroll
        for (int c = 0; c < 4; ++c)
          acc[r][c] = __builtin_amdgcn_mfma_f32_16x16x32_bf16(a[r], bh_c[c], acc[r][c], 0, 0, 0);
#pragma unroll
      for (int c = 0; c < 4; ++c) bh_c[c] = bh_n[c];
    }
    __syncthreads();
    xv_next = xv_pf;
  }
  // epilogue: C/D layout col=lane&15, row=quad*4+reg (verified m89/m91).
  // pack c-pairs: p = q*16 + m, q = 2w + cp -> cols (q*32+m, q*32+16+m)
#pragma unroll
  for (int r = 0; r < 4; ++r) {
#pragma unroll
    for (int reg = 0; reg < 4; ++reg) {
      int nd = block0 + r * 16 + quad * 4 + reg;
      if (nd < NN) {
#pragma unroll
        for (int cp = 0; cp < 2; ++cp) {
          int q = 2 * w + cp;
          uint val = (uint)bf16_rne(acc[r][2 * cp][reg]) |
                     ((uint)bf16_rne(acc[r][2 * cp + 1][reg]) << 16);
          projB[(size_t)nd * 128 + q * 16 + m] = val;
        }
      }
    }
  }
}

// ---- CSR build ----
__global__ __launch_bounds__(256) void scanA_kernel(
    const int* __restrict__ deg, int* __restrict__ ex, int* __restrict__ partial) {
  __shared__ int sd[256];
  int t = threadIdx.x;
  int idx = blockIdx.x * 256 + t;
  int v = (idx < NN) ? deg[idx] : 0;
  sd[t] = v;
  __syncthreads();
#pragma unroll
  for (int off = 1; off < 256; off <<= 1) {
    int add = (t >= off) ? sd[t - off] : 0;
    __syncthreads();
    sd[t] += add;
    __syncthreads();
  }
  if (idx < NN) ex[idx] = sd[t] - v;
  if (t == 255) partial[blockIdx.x] = sd[255];
}

__global__ __launch_bounds__(256) void scanB_kernel(
    const int* __restrict__ partial, int* __restrict__ poff, int nblk) {
  __shared__ int sd[256];
  int t = threadIdx.x;
  int v = (t < nblk) ? partial[t] : 0;
  sd[t] = v;
  __syncthreads();
#pragma unroll
  for (int off = 1; off < 256; off <<= 1) {
    int add = (t >= off) ? sd[t - off] : 0;
    __syncthreads();
    sd[t] += add;
    __syncthreads();
  }
  if (t < nblk) poff[t] = sd[t] - v;
}

__global__ __launch_bounds__(256) void scanC_kernel(
    const int* __restrict__ ex, const int* __restrict__ poff,
    int* __restrict__ row_ptr, int* __restrict__ cur) {
  int idx = blockIdx.x * 256 + threadIdx.x;
  if (idx < NN) {
    int v = ex[idx] + poff[idx >> 8];
    row_ptr[idx] = v;
    cur[idx] = v;
  }
  if (idx == 0) row_ptr[NN] = EE;
}

// 2 edges/thread, int2 loads; store SRC id directly
__global__ __launch_bounds__(256) void fill_kernel(
    const int* __restrict__ ei, int* __restrict__ cur, int* __restrict__ scsr) {
  int base = (blockIdx.x * 256 + threadIdx.x) * 2;
  if (base + 1 < EE) {
    int2 ss = *(const int2*)(ei + base);
    int2 dd = *(const int2*)(ei + EE + base);
    int p0 = atomicAdd(&cur[dd.x], 1);
    scsr[p0] = ss.x;
    int p1 = atomicAdd(&cur[dd.y], 1);
    scsr[p1] = ss.y;
  } else if (base < EE) {
    int s = ei[base], d = ei[EE + base];
    scsr[atomicAdd(&cur[d], 1)] = s;
  }
}

// Per-dst aggregation: one wave per dst, 4 edges in flight (16-lane groups),
// 2-deep gather pipeline (src idx 3 ahead, row data 2 ahead).
// Lane l: group g=l>>4, m=l&15 -> uint4 = p 4m..4m+3 (head m>>2 only) ->
// score reduce = 2 shfls. Cross-group combine once; fused epilogue.
__global__ __launch_bounds__(256) void aggr_kernel(
    const uint* __restrict__ projB, const int* __restrict__ scsr,
    const int* __restrict__ row_ptr, const float* __restrict__ av,
    const float* __restrict__ x, const float* __restrict__ bias,
    const float* __restrict__ pa, float* __restrict__ out) {
  int d = blockIdx.x * 4 + (threadIdx.x >> 6);
  if (d >= NN) return;
  int l = threadIdx.x & 63;
  int g = l >> 4, m = l & 15;
  const uint4* pb4 = (const uint4*)projB;
  uint4 dpu = pb4[(size_t)d * 32 + 16 + m];
  uint du[4] = {dpu.x, dpu.y, dpu.z, dpu.w};
  float dplo[4], dphi[4], avlo[4], avhi[4];
  int cl[4];
#pragma unroll
  for (int j = 0; j < 4; ++j) {
    dplo[j] = bf_lo(du[j]);
    dphi[j] = bf_hi(du[j]);
    int p = 4 * m + j;
    cl[j] = ((p >> 4) << 5) + (p & 15);
    avlo[j] = av[cl[j]];
    avhi[j] = av[cl[j] + 16];
  }
  int i0 = row_ptr[d], i1 = row_ptr[d + 1];
  float acl[4] = {0.f, 0.f, 0.f, 0.f}, ach[4] = {0.f, 0.f, 0.f, 0.f};
  float den = 0.f;
  int i = i0 + g;
  if (i < i1) {
    int s0 = scsr[i];
    int s1 = (i + 4 < i1) ? scsr[i + 4] : s0;
    int s2 = (i + 8 < i1) ? scsr[i + 8] : s1;
    uint4 U0 = pb4[(size_t)s0 * 32 + m];
    uint4 U1 = pb4[(size_t)s1 * 32 + m];
    for (; i < i1; i += 4) {
      int s3 = (i + 12 < i1) ? scsr[i + 12] : s2;
      uint4 U2 = pb4[(size_t)s2 * 32 + m];  // 2-ahead, issues immediately
      uint uu[4] = {U0.x, U0.y, U0.z, U0.w};
      float slo[4], shi[4];
      float vp = 0.f;
#pragma unroll
      for (int j = 0; j < 4; ++j) {
        slo[j] = bf_lo(uu[j]);
        shi[j] = bf_hi(uu[j]);
        float v0 = slo[j] + dplo[j];
        float v1 = shi[j] + dphi[j];
        v0 = (v0 >= 0.f) ? v0 : 0.2f * v0;
        v1 = (v1 >= 0.f) ? v1 : 0.2f * v1;
        vp = fmaf(v0, avlo[j], vp);
        vp = fmaf(v1, avhi[j], vp);
      }
      vp += __shfl_xor(vp, 1, 64);  // head-local reduce (4-lane subgroup)
      vp += __shfl_xor(vp, 2, 64);
      float e = __expf(vp);
#pragma unroll
      for (int j = 0; j < 4; ++j) {
        acl[j] = fmaf(e, slo[j], acl[j]);
        ach[j] = fmaf(e, shi[j], ach[j]);
      }
      den += e;
      U0 = U1;
      U1 = U2;
      s2 = s3;
    }
  }
  // combine the 4 edge-groups (heads preserved: lanes with same m align)
#pragma unroll
  for (int off = 16; off < 64; off <<= 1) {
    den += __shfl_xor(den, off, 64);
#pragma unroll
    for (int j = 0; j < 4; ++j) {
      acl[j] += __shfl_xor(acl[j], off, 64);
      ach[j] += __shfl_xor(ach[j], off, 64);
    }
  }
  if (g == 0) {
    float a = pa[0];
    float r = 1.f / (den + 1e-16f);
#pragma unroll
    for (int j = 0; j < 4; ++j) {
      float o0 = acl[j] * r + x[(size_t)d * FF + cl[j]] + bias[cl[j]];
      float o1 = ach[j] * r + x[(size_t)d * FF + cl[j] + 16] + bias[cl[j] + 16];
      out[(size_t)d * FF + cl[j]] = (o0 >= 0.f) ? o0 : a * o0;
      out[(size_t)d * FF + cl[j] + 16] = (o1 >= 0.f) ? o1 : a * o1;
    }
  }
}

extern "C" void kernel_launch(void* const* d_in, const int* in_sizes, int n_in,
                              void* d_out, int out_size, void* d_ws, size_t ws_size,
                              hipStream_t stream) {
  const float* x = (const float*)d_in[0];
  const int* ei = (const int*)d_in[1];
  const float* bws = (const float*)d_in[2];
  const float* sws = (const float*)d_in[3];
  const float* bwd = (const float*)d_in[4];
  const float* swd = (const float*)d_in[5];
  const float* av = (const float*)d_in[6];
  const float* bias = (const float*)d_in[7];
  const float* pa = (const float*)d_in[8];

  // ws layout: Wh | projB | deg | ex | cur | row_ptr | partial | poff | scsr
  ushort* Wh = (ushort*)d_ws;
  uint* projB = (uint*)(Wh + (size_t)O2 * KT);
  int* deg = (int*)(projB + (size_t)NN * 128);
  int* ex = deg + NN;
  int* cur = ex + NN;
  int* row_ptr = cur + NN;         // NN+1 entries
  int* partial = row_ptr + NN + 1;
  int* poff = partial + 256;
  int* scsr = poff + 256;

  const int NB = (NN + 255) / 256;  // 196 scan blocks

  repack_zero_kernel<<<(O2 * KT + 255) / 256, 256, 0, stream>>>(bws, sws, bwd, swd, Wh, deg);
  proj_count_kernel<<<NPB + NCB, 256, 0, stream>>>(x, Wh, projB, ei, deg);
  scanA_kernel<<<NB, 256, 0, stream>>>(deg, ex, partial);
  scanB_kernel<<<1, 256, 0, stream>>>(partial, poff, NB);
  scanC_kernel<<<NB, 256, 0, stream>>>(ex, poff, row_ptr, cur);
  fill_kernel<<<(EE / 2 + 255) / 256, 256, 0, stream>>>(ei, cur, scsr);
  aggr_kernel<<<(NN + 3) / 4, 256, 0, stream>>>(projB, scsr, row_ptr, av, x, bias, pa,
                                                (float*)d_out);
}